// Round 1
// baseline (4625.052 us; speedup 1.0000x reference)
//
#include <hip/hip_runtime.h>
#include <math.h>

// Problem constants
#define Bn   8
#define Nn   64
#define Rn   2048
#define Dn   4096
#define Hn   512
#define NOc  151
#define NRc  51
#define Tt   3
#define BNt  (Bn*Nn)   // 512 objects total
#define BRt  (Bn*Rn)   // 16384 relations total

__device__ __forceinline__ float sigmf(float x){ return 1.0f/(1.0f+expf(-x)); }

// ---------------------------------------------------------------------------
// Generic guarded SGEMM: C[M,N] = act( A[M,K]@B[K,N] (+ beta*C) (+ bias) )
// act: 0=none 1=sigmoid 2=tanh. BM*BK==1024 and BK*BN==1024 (1 float4/thread).
// ---------------------------------------------------------------------------
template<int BM,int BN,int BK,int TM,int TN>
__global__ __launch_bounds__(256)
void gemm_kernel(const float* __restrict__ A, const float* __restrict__ Bm,
                 float* __restrict__ C, int M,int N,int K,int lda,int ldb,int ldc,
                 const float* __restrict__ bias, int beta, int act)
{
  __shared__ float As[BK][BM+4];
  __shared__ float Bs[BK][BN+4];
  const int tid = threadIdx.x;
  const int bm = blockIdx.y*BM;
  const int bn = blockIdx.x*BN;
  constexpr int AK4 = BK/4;
  const int a_m = tid/AK4;
  const int a_k = (tid%AK4)*4;
  constexpr int BN4 = BN/4;
  const int b_kr = tid/BN4;
  const int b_n  = (tid%BN4)*4;
  constexpr int NTX = BN/TN;
  const int tx = tid%NTX, ty = tid/NTX;
  const int cm = ty*TM, cn = tx*TN;
  const bool avec = ((lda&3)==0);
  const bool bvec = ((ldb&3)==0);

  float acc[TM][TN];
#pragma unroll
  for(int i=0;i<TM;i++)
#pragma unroll
    for(int j=0;j<TN;j++) acc[i][j]=0.f;

  for(int k0=0;k0<K;k0+=BK){
    float4 av=make_float4(0.f,0.f,0.f,0.f);
    {
      int gm=bm+a_m, gk=k0+a_k;
      if(gm<M && gk<K){
        const float* p=A+(size_t)gm*lda+gk;
        if(avec && gk+3<K) av=*(const float4*)p;
        else{
          av.x=p[0];
          if(gk+1<K)av.y=p[1];
          if(gk+2<K)av.z=p[2];
          if(gk+3<K)av.w=p[3];
        }
      }
    }
    float4 bv=make_float4(0.f,0.f,0.f,0.f);
    {
      int gk=k0+b_kr, gn=bn+b_n;
      if(gk<K && gn<N){
        const float* p=Bm+(size_t)gk*ldb+gn;
        if(bvec && gn+3<N) bv=*(const float4*)p;
        else{
          bv.x=p[0];
          if(gn+1<N)bv.y=p[1];
          if(gn+2<N)bv.z=p[2];
          if(gn+3<N)bv.w=p[3];
        }
      }
    }
    As[a_k+0][a_m]=av.x; As[a_k+1][a_m]=av.y; As[a_k+2][a_m]=av.z; As[a_k+3][a_m]=av.w;
    *(float4*)(&Bs[b_kr][b_n])=bv;
    __syncthreads();
#pragma unroll
    for(int kk=0;kk<BK;kk++){
      float ar[TM], brg[TN];
#pragma unroll
      for(int i=0;i<TM;i++) ar[i]=As[kk][cm+i];
#pragma unroll
      for(int j=0;j<TN;j++) brg[j]=Bs[kk][cn+j];
#pragma unroll
      for(int i=0;i<TM;i++)
#pragma unroll
        for(int j=0;j<TN;j++) acc[i][j]=fmaf(ar[i],brg[j],acc[i][j]);
    }
    __syncthreads();
  }
#pragma unroll
  for(int i=0;i<TM;i++){
    int gm=bm+cm+i; if(gm>=M) break;
#pragma unroll
    for(int j=0;j<TN;j++){
      int gn=bn+cn+j; if(gn>=N) continue;
      float v=acc[i][j];
      if(beta) v+=C[(size_t)gm*ldc+gn];
      if(bias) v+=bias[gn];
      if(act==1) v=sigmf(v);
      else if(act==2) v=tanhf(v);
      C[(size_t)gm*ldc+gn]=v;
    }
  }
}

// ---------------------------------------------------------------------------
// Row softmax: one wave per row.
// ---------------------------------------------------------------------------
__global__ __launch_bounds__(64)
void softmax_kernel(const float* __restrict__ in, float* __restrict__ out,
                    int cols, int ldi, int ldo)
{
  int row = blockIdx.x, lane = threadIdx.x;
  const float* rp = in + (size_t)row*ldi;
  float m = -INFINITY;
  for (int c = lane; c < cols; c += 64) m = fmaxf(m, rp[c]);
  for (int off = 32; off; off >>= 1) m = fmaxf(m, __shfl_xor(m, off));
  float s = 0.f;
  for (int c = lane; c < cols; c += 64) s += expf(rp[c]-m);
  for (int off = 32; off; off >>= 1) s += __shfl_xor(s, off);
  float inv = 1.f/s;
  float* op = out + (size_t)row*ldo;
  for (int c = lane; c < cols; c += 64) op[c] = expf(rp[c]-m)*inv;
}

// argmax over cols [1, NOc) ; result index written as float (== argmax[1:]+1)
__global__ __launch_bounds__(64)
void argmax_kernel(const float* __restrict__ ref, float* __restrict__ preds)
{
  int row = blockIdx.x, lane = threadIdx.x;
  const float* rp = ref + (size_t)row*NOc;
  float bv = -INFINITY; int bi = NOc;
  for (int c = 1+lane; c < NOc; c += 64) { float v = rp[c]; if (v > bv) { bv=v; bi=c; } }
  for (int off=32; off; off>>=1) {
    float ov = __shfl_xor(bv, off); int oi = __shfl_xor(bi, off);
    if (ov > bv || (ov == bv && oi < bi)) { bv = ov; bi = oi; }
  }
  if (lane==0) preds[row] = (float)bi;
}

// pack [Wz|Wr|Wh] -> [512,1536]
__global__ __launch_bounds__(256)
void pack3_kernel(const float* __restrict__ a, const float* __restrict__ b,
                  const float* __restrict__ c, float* __restrict__ out)
{
  int idx = blockIdx.x*256 + threadIdx.x;
  if (idx >= Hn*3*Hn) return;
  int r = idx / (3*Hn), col = idx % (3*Hn);
  float v;
  if (col < Hn) v = a[(size_t)r*Hn+col];
  else if (col < 2*Hn) v = b[(size_t)r*Hn+col-Hn];
  else v = c[(size_t)r*Hn+col-2*Hn];
  out[idx] = v;
}

// pack [Uz|Ur] -> [512,1024]
__global__ __launch_bounds__(256)
void pack2_kernel(const float* __restrict__ a, const float* __restrict__ b,
                  float* __restrict__ out)
{
  int idx = blockIdx.x*256 + threadIdx.x;
  if (idx >= Hn*2*Hn) return;
  int r = idx / (2*Hn), col = idx % (2*Hn);
  out[idx] = (col < Hn) ? a[(size_t)r*Hn+col] : b[(size_t)r*Hn+col-Hn];
}

// Segment sums of hr rows into SumS/SumO [512,512] (global obj index).
// grid: (hchunk=8, seg=4, img=8), block 64. Each thread owns one h column.
__global__ __launch_bounds__(64)
void segsum_kernel(const float* __restrict__ hr, const int* __restrict__ rel_inds,
                   float* __restrict__ SumS, float* __restrict__ SumO)
{
  __shared__ float accS[Nn][64];
  __shared__ float accO[Nn][64];
  const int t = threadIdx.x;
  const int hb = blockIdx.x * 64;
  const int img = blockIdx.z;
  const int relbase = img*Rn + blockIdx.y*(Rn/4);
  for (int o = 0; o < Nn; o++) { accS[o][t] = 0.f; accO[o][t] = 0.f; }
  for (int i = 0; i < Rn/4; i++) {
    int r = relbase + i;
    int s = rel_inds[r*3+1] - img*Nn;   // local 0..63
    int o = rel_inds[r*3+2] - img*Nn;
    float v = hr[(size_t)r*Hn + hb + t];
    accS[s][t] += v;
    accO[o][t] += v;
  }
  for (int ob = 0; ob < Nn; ob++) {
    atomicAdd(&SumS[(size_t)(img*Nn+ob)*Hn + hb + t], accS[ob][t]);
    atomicAdd(&SumO[(size_t)(img*Nn+ob)*Hn + hb + t], accO[ob][t]);
  }
}

// Rel GRU stage A: z = sig(gather_z + hU_z + bz); rh = sig(gather_r + hU_r + br)*hr
__global__ __launch_bounds__(256)
void gru_rel_A(const int* __restrict__ rel, const float* __restrict__ Gs,
               const float* __restrict__ Go, const float* __restrict__ hU,
               const float* __restrict__ bz, const float* __restrict__ br,
               const float* __restrict__ hr, float* __restrict__ Z,
               float* __restrict__ RH)
{
  int idx = blockIdx.x*256 + threadIdx.x;
  if (idx >= BRt*Hn) return;
  int r = idx >> 9;
  int h = idx & (Hn-1);
  int s = rel[r*3+1];
  int o = rel[r*3+2];
  float z  = sigmf(Gs[(size_t)s*1536+h]      + Go[(size_t)o*1536+h]      + hU[(size_t)r*1024+h]      + bz[h]);
  float rr = sigmf(Gs[(size_t)s*1536+Hn+h]   + Go[(size_t)o*1536+Hn+h]   + hU[(size_t)r*1024+Hn+h]   + br[h]);
  Z[idx]  = z;
  RH[idx] = rr * hr[idx];
}

// Rel GRU stage B: hh = tanh(gather_h + rhU + bh); hr = (1-z)hr + z*hh
__global__ __launch_bounds__(256)
void gru_rel_B(const int* __restrict__ rel, const float* __restrict__ Gs,
               const float* __restrict__ Go, const float* __restrict__ rhU,
               const float* __restrict__ bh, const float* __restrict__ Z,
               float* __restrict__ hr)
{
  int idx = blockIdx.x*256 + threadIdx.x;
  if (idx >= BRt*Hn) return;
  int r = idx >> 9;
  int h = idx & (Hn-1);
  int s = rel[r*3+1];
  int o = rel[r*3+2];
  float hh = tanhf(Gs[(size_t)s*1536+2*Hn+h] + Go[(size_t)o*1536+2*Hn+h] + rhU[idx] + bh[h]);
  float z = Z[idx];
  float hv = hr[idx];
  hr[idx] = (1.f-z)*hv + z*hh;
}

__global__ __launch_bounds__(256)
void ew_mul_kernel(float* __restrict__ a, const float* __restrict__ b, int n)
{
  int i = blockIdx.x*256 + threadIdx.x;
  if (i < n) a[i] = a[i]*b[i];
}

__global__ __launch_bounds__(256)
void ew_upd_kernel(float* __restrict__ h, const float* __restrict__ z,
                   const float* __restrict__ hh, int n)
{
  int i = blockIdx.x*256 + threadIdx.x;
  if (i < n) { float zz = z[i]; h[i] = (1.f-zz)*h[i] + zz*hh[i]; }
}

// ---------------------------------------------------------------------------
// Host wrappers
// ---------------------------------------------------------------------------
static void gemmL(hipStream_t s,const float*A,const float*B,float*C,int M,int N,int K,
                  int lda,int ldb,int ldc,const float*bias,int beta,int act){
  dim3 g((N+127)/128,(M+127)/128);
  gemm_kernel<128,128,8,8,8><<<g,256,0,s>>>(A,B,C,M,N,K,lda,ldb,ldc,bias,beta,act);
}
static void gemmM(hipStream_t s,const float*A,const float*B,float*C,int M,int N,int K,
                  int lda,int ldb,int ldc,const float*bias,int beta,int act){
  dim3 g((N+63)/64,(M+63)/64);
  gemm_kernel<64,64,16,4,4><<<g,256,0,s>>>(A,B,C,M,N,K,lda,ldb,ldc,bias,beta,act);
}
static void gemmS(hipStream_t s,const float*A,const float*B,float*C,int M,int N,int K,
                  int lda,int ldb,int ldc,const float*bias,int beta,int act){
  dim3 g((N+31)/32,(M+31)/32);
  gemm_kernel<32,32,32,2,2><<<g,256,0,s>>>(A,B,C,M,N,K,lda,ldb,ldc,bias,beta,act);
}

extern "C" void kernel_launch(void* const* d_in, const int* in_sizes, int n_in,
                              void* d_out, int out_size, void* d_ws, size_t ws_size,
                              hipStream_t stream) {
  (void)in_sizes; (void)n_in; (void)out_size; (void)ws_size;
  const int*   rel_inds   = (const int*)  d_in[1];
  const float* obj_fmaps  = (const float*)d_in[2];
  const float* obj_logits = (const float*)d_in[3];
  const float* vr         = (const float*)d_in[4];
  const float* W_obj      = (const float*)d_in[5];
  const float* b_obj      = (const float*)d_in[6];
  const float* W_rel      = (const float*)d_in[7];
  const float* b_rel      = (const float*)d_in[8];
  const float* W_prob     = (const float*)d_in[9];
  const float* b_prob     = (const float*)d_in[10];
  const float* W_so       = (const float*)d_in[11];
  const float* W_oo       = (const float*)d_in[12];
  const float* W_rs       = (const float*)d_in[13];
  const float* W_ro       = (const float*)d_in[14];
  const float* Wz         = (const float*)d_in[15];
  const float* Uz         = (const float*)d_in[16];
  const float* bz         = (const float*)d_in[17];
  const float* Wr         = (const float*)d_in[18];
  const float* Ur         = (const float*)d_in[19];
  const float* br         = (const float*)d_in[20];
  const float* Wh         = (const float*)d_in[21];
  const float* Uh         = (const float*)d_in[22];
  const float* bh         = (const float*)d_in[23];
  const float* W_out_rel  = (const float*)d_in[24];
  const float* b_out_rel  = (const float*)d_in[25];
  const float* W_cls_rel  = (const float*)d_in[26];
  const float* b_cls_rel  = (const float*)d_in[27];
  const float* W_out_obj  = (const float*)d_in[28];
  const float* b_out_obj  = (const float*)d_in[29];
  const float* W_cls_obj  = (const float*)d_in[30];
  const float* b_cls_obj  = (const float*)d_in[31];

  // output layout (floats): obj_ref | obj_preds | rel_logits | scpred | scent
  float* out          = (float*)d_out;
  float* out_obj_ref  = out;                          // 512*151
  float* out_preds    = out + 77312;                  // 512
  float* out_rel_log  = out + 77824;                  // 16384*51
  float* out_scpred   = out + 913408;                 // 16384*51
  float* out_scent    = out + 1748992;                // 512*151

  // workspace carve (all counts multiples of 64 floats -> 16B aligned)
  float* P = (float*)d_ws; size_t off = 0;
  auto A_ = [&](size_t n){ float* p = P + off; off += n; return p; };
  float* obj_probs = A_(512*152);        // padded ld=152
  float* xo   = A_(512*512);
  float* xr   = A_((size_t)BRt*Hn);
  float* ho   = A_(512*512);
  float* hr   = A_((size_t)BRt*Hn);
  float* cat3 = A_(512*1536);
  float* WsoW = A_(512*1536);
  float* WooW = A_(512*1536);
  float* catU = A_(512*1024);
  float* Gs   = A_(512*1536);
  float* Go   = A_(512*1536);
  float* SumS = A_(512*512);             // SumS,SumO contiguous for one memset
  float* SumO = A_(512*512);
  float* mo   = A_(512*512);
  float* zo   = A_(512*512);
  float* ro   = A_(512*512);
  float* hho  = A_(512*512);
  float* Cobj = A_(512*512);
  float* hU   = A_((size_t)BRt*1024);
  float* Zb   = A_((size_t)BRt*Hn);
  float* RH   = A_((size_t)BRt*Hn);
  float* rhU  = hU;    // alias: hU fully consumed before rhU is produced
  float* Crel = hU;    // alias: hU free after the T loop

  const int nRel = BRt*Hn;          // 8,388,608
  const int nObj = 512*512;         // 262,144

  // ---- setup ----
  softmax_kernel<<<512,64,0,stream>>>(obj_logits, obj_probs, NOc, NOc, 152);
  gemmM(stream, obj_fmaps, W_obj, xo, 512,512,Dn, Dn,512,512, b_obj,0,0);
  gemmM(stream, obj_probs, W_prob, xo, 512,512,NOc, 152,512,512, b_prob,1,0);
  gemmL(stream, vr, W_rel, xr, BRt,512,Dn, Dn,512,512, b_rel,0,0);
  hipMemcpyAsync(ho, xo, (size_t)nObj*sizeof(float), hipMemcpyDeviceToDevice, stream);
  hipMemcpyAsync(hr, xr, (size_t)nRel*sizeof(float), hipMemcpyDeviceToDevice, stream);
  pack3_kernel<<<(512*1536+255)/256,256,0,stream>>>(Wz, Wr, Wh, cat3);
  pack2_kernel<<<(512*1024+255)/256,256,0,stream>>>(Uz, Ur, catU);
  gemmM(stream, W_so, cat3, WsoW, 512,1536,512, 512,1536,1536, nullptr,0,0);
  gemmM(stream, W_oo, cat3, WooW, 512,1536,512, 512,1536,1536, nullptr,0,0);

  // ---- T GGNN steps ----
  for (int t = 0; t < Tt; t++) {
    // rel-message projections of OLD ho:  Gs = ho@(W_so@[Wz|Wr|Wh]), Go likewise
    gemmM(stream, ho, WsoW, Gs, 512,1536,512, 512,1536,1536, nullptr,0,0);
    gemmM(stream, ho, WooW, Go, 512,1536,512, 512,1536,1536, nullptr,0,0);
    // obj-message segment sums of OLD hr
    hipMemsetAsync(SumS, 0, 2*(size_t)nObj*sizeof(float), stream);
    segsum_kernel<<<dim3(8,4,8),64,0,stream>>>(hr, rel_inds, SumS, SumO);
    // hU = hr@[Uz|Ur]
    gemmL(stream, hr, catU, hU, BRt,1024,512, 512,1024,512*2, nullptr,0,0);
    // rel GRU
    gru_rel_A<<<(nRel+255)/256,256,0,stream>>>(rel_inds, Gs, Go, hU, bz, br, hr, Zb, RH);
    gemmL(stream, RH, Uh, rhU, BRt,512,512, 512,512,512, nullptr,0,0);
    gru_rel_B<<<(nRel+255)/256,256,0,stream>>>(rel_inds, Gs, Go, rhU, bh, Zb, hr);
    // obj GRU: mo = SumS@W_rs + SumO@W_ro
    gemmS(stream, SumS, W_rs, mo, 512,512,512, 512,512,512, nullptr,0,0);
    gemmS(stream, SumO, W_ro, mo, 512,512,512, 512,512,512, nullptr,1,0);
    gemmS(stream, mo, Wz, zo, 512,512,512, 512,512,512, nullptr,0,0);
    gemmS(stream, ho, Uz, zo, 512,512,512, 512,512,512, bz,1,1);
    gemmS(stream, mo, Wr, ro, 512,512,512, 512,512,512, nullptr,0,0);
    gemmS(stream, ho, Ur, ro, 512,512,512, 512,512,512, br,1,1);
    ew_mul_kernel<<<(nObj+255)/256,256,0,stream>>>(ro, ho, nObj);
    gemmS(stream, mo, Wh, hho, 512,512,512, 512,512,512, nullptr,0,0);
    gemmS(stream, ro, Uh, hho, 512,512,512, 512,512,512, bh,1,2);
    ew_upd_kernel<<<(nObj+255)/256,256,0,stream>>>(ho, zo, hho, nObj);
  }

  // ---- heads ----
  // rel: Crel = tanh([hr|xr]@W_out_rel + b); rel_logits = Crel@W_cls_rel + b
  gemmL(stream, hr, W_out_rel, Crel, BRt,512,512, 512,512,512, nullptr,0,0);
  gemmL(stream, xr, W_out_rel+512*512, Crel, BRt,512,512, 512,512,512, b_out_rel,1,2);
  gemmM(stream, Crel, W_cls_rel, out_rel_log, BRt,NRc,512, 512,NRc,NRc, b_cls_rel,0,0);
  softmax_kernel<<<BRt,64,0,stream>>>(out_rel_log, out_scpred, NRc, NRc, NRc);
  // obj: Cobj = tanh([ho|xo]@W_out_obj + b); obj_ref = Cobj@W_cls_obj + b
  gemmS(stream, ho, W_out_obj, Cobj, 512,512,512, 512,512,512, nullptr,0,0);
  gemmS(stream, xo, W_out_obj+512*512, Cobj, 512,512,512, 512,512,512, b_out_obj,1,2);
  gemmS(stream, Cobj, W_cls_obj, out_obj_ref, 512,NOc,512, 512,NOc,NOc, b_cls_obj,0,0);
  softmax_kernel<<<512,64,0,stream>>>(out_obj_ref, out_scent, NOc, NOc, NOc);
  argmax_kernel<<<512,64,0,stream>>>(out_obj_ref, out_preds);
}

// Round 2
// 2295.490 us; speedup vs baseline: 2.0148x; 2.0148x over previous
//
#include <hip/hip_runtime.h>
#include <math.h>

// Problem constants
#define Bn   8
#define Nn   64
#define Rn   2048
#define Dn   4096
#define Hn   512
#define NOc  151
#define NRc  51
#define Tt   3
#define BNt  (Bn*Nn)   // 512 objects
#define BRt  (Bn*Rn)   // 16384 relations

typedef __attribute__((ext_vector_type(8))) short short8;
typedef __attribute__((ext_vector_type(4))) float f32x4;

__device__ __forceinline__ float sigmf(float x){ return 1.0f/(1.0f+expf(-x)); }

__device__ __forceinline__ ushort f2bf_rne(float x){
  unsigned u = __float_as_uint(x);
  unsigned r = u + 0x7FFFu + ((u>>16)&1u);
  return (ushort)(r>>16);
}

// ---------------------------------------------------------------------------
// bf16x3 MFMA GEMM: C[M,N] = act( A_f32[M,K] @ B (+beta*C) (+bias) )
// B is pre-split bf16 hi/lo planes in [N][Kld] layout (k-contiguous, k-padded
// to 32 with zeros). A is split to bf16 hi/lo in-kernel during LDS staging.
// C = Ah*Bh + Ah*Bl + Al*Bh accumulated in fp32 (rel err ~3e-5 vs fp32).
// ---------------------------------------------------------------------------
template<int BM,int BN>
__global__ __launch_bounds__(256)
void gemm_b3(const float* __restrict__ A, const ushort* __restrict__ Bhg,
             const ushort* __restrict__ Blg, float* __restrict__ C,
             int M,int N,int K,int lda,int ldb,int ldc,
             const float* __restrict__ bias,int beta,int act)
{
  constexpr int MT = BM/32, NT = BN/32;
  __shared__ ushort Ah[BM*40], Al[BM*40], Bh[BN*40], Bl[BN*40];
  const int tid  = threadIdx.x;
  const int lane = tid & 63;
  const int wid  = tid >> 6;
  const int quad = lane >> 4, l15 = lane & 15;
  const int wm = (wid>>1)*(BM/2), wn = (wid&1)*(BN/2);
  const int bm = blockIdx.y*BM, bn = blockIdx.x*BN;

  constexpr int TPR  = 256/BM;      // threads per A row
  constexpr int FPT  = 32/TPR;      // floats per thread (A)
  const int ar = tid / TPR;
  const int ak = (tid % TPR) * FPT;
  constexpr int TPRB = 256/BN;
  constexpr int SPT  = 32/TPRB;     // shorts per thread per B plane
  const int br = tid / TPRB;
  const int bk = (tid % TPRB) * SPT;
  const int grA = bm + ar;
  const int grB = bn + br;

  f32x4 acc[MT][NT];
#pragma unroll
  for (int i=0;i<MT;i++)
#pragma unroll
    for (int j=0;j<NT;j++) acc[i][j] = (f32x4){0.f,0.f,0.f,0.f};

  for (int k0=0; k0<K; k0+=32) {
    // ---- stage A (fp32 -> bf16 hi/lo) ----
    {
      float av[FPT];
      if (grA < M && k0 + ak + FPT <= K) {
        const float* p = A + (size_t)grA*lda + k0 + ak;
#pragma unroll
        for (int i=0;i<FPT/4;i++) ((float4*)av)[i] = ((const float4*)p)[i];
      } else {
#pragma unroll
        for (int i=0;i<FPT;i++){
          int gk = k0+ak+i;
          av[i] = (grA<M && gk<K) ? A[(size_t)grA*lda+gk] : 0.f;
        }
      }
      ushort hs[FPT], ls[FPT];
#pragma unroll
      for (int i=0;i<FPT;i++){
        ushort h = f2bf_rne(av[i]);
        float hf = __uint_as_float(((unsigned)h)<<16);
        hs[i]=h; ls[i]=f2bf_rne(av[i]-hf);
      }
#pragma unroll
      for (int i=0;i<FPT;i+=8){
        short8 vh, vl;
#pragma unroll
        for (int q=0;q<8;q++){ vh[q]=(short)hs[i+q]; vl[q]=(short)ls[i+q]; }
        *(short8*)&Ah[ar*40+ak+i] = vh;
        *(short8*)&Al[ar*40+ak+i] = vl;
      }
    }
    // ---- stage B (pre-split bf16) ----
    {
#pragma unroll
      for (int i=0;i<SPT;i+=8){
        short8 vh, vl;
        if (grB < N){
          vh = *(const short8*)(Bhg + (size_t)grB*ldb + k0 + bk + i);
          vl = *(const short8*)(Blg + (size_t)grB*ldb + k0 + bk + i);
        } else {
#pragma unroll
          for (int q=0;q<8;q++){ vh[q]=0; vl[q]=0; }
        }
        *(short8*)&Bh[br*40+bk+i] = vh;
        *(short8*)&Bl[br*40+bk+i] = vl;
      }
    }
    __syncthreads();
    // ---- fragments + MFMA ----
    {
      short8 afh[MT], afl[MT], bfh[NT], bfl[NT];
#pragma unroll
      for (int i=0;i<MT;i++){
        int o = (wm + i*16 + l15)*40 + quad*8;
        afh[i] = *(const short8*)&Ah[o];
        afl[i] = *(const short8*)&Al[o];
      }
#pragma unroll
      for (int j=0;j<NT;j++){
        int o = (wn + j*16 + l15)*40 + quad*8;
        bfh[j] = *(const short8*)&Bh[o];
        bfl[j] = *(const short8*)&Bl[o];
      }
#pragma unroll
      for (int i=0;i<MT;i++)
#pragma unroll
        for (int j=0;j<NT;j++)
          acc[i][j] = __builtin_amdgcn_mfma_f32_16x16x32_bf16(afh[i], bfh[j], acc[i][j], 0,0,0);
#pragma unroll
      for (int i=0;i<MT;i++)
#pragma unroll
        for (int j=0;j<NT;j++)
          acc[i][j] = __builtin_amdgcn_mfma_f32_16x16x32_bf16(afh[i], bfl[j], acc[i][j], 0,0,0);
#pragma unroll
      for (int i=0;i<MT;i++)
#pragma unroll
        for (int j=0;j<NT;j++)
          acc[i][j] = __builtin_amdgcn_mfma_f32_16x16x32_bf16(afl[i], bfh[j], acc[i][j], 0,0,0);
    }
    __syncthreads();
  }
  // ---- epilogue: C/D layout col=lane&15, row=quad*4+reg ----
#pragma unroll
  for (int i=0;i<MT;i++){
    int gm0 = bm + wm + i*16 + quad*4;
#pragma unroll
    for (int j=0;j<NT;j++){
      int gn = bn + wn + j*16 + l15;
      if (gn >= N) continue;
#pragma unroll
      for (int r=0;r<4;r++){
        int gm = gm0 + r;
        if (gm >= M) continue;
        float v = acc[i][j][r];
        if (beta) v += C[(size_t)gm*ldc+gn];
        if (bias) v += bias[gn];
        if (act==1) v = sigmf(v);
        else if (act==2) v = tanhf(v);
        C[(size_t)gm*ldc+gn] = v;
      }
    }
  }
}

// ---------------------------------------------------------------------------
// Transpose+split weight: src fp32 [K][N] (ld N) -> dh/dl bf16 [rowoff+n][koff+k]
// (ld dld). k >= K (up to gridDim.x*32) written as zero (K-padding).
// ---------------------------------------------------------------------------
__global__ __launch_bounds__(256)
void tsplit(const float* __restrict__ src,int K,int N,
            ushort* __restrict__ dh, ushort* __restrict__ dl,
            int dld,int rowoff,int koff)
{
  __shared__ float t[32][33];
  const int tx = threadIdx.x, ty = threadIdx.y;
  const int kb = blockIdx.x*32, nb = blockIdx.y*32;
#pragma unroll
  for (int r=0;r<4;r++){
    int k = kb + ty + r*8, n = nb + tx;
    t[ty+r*8][tx] = (k<K && n<N) ? src[(size_t)k*N + n] : 0.f;
  }
  __syncthreads();
#pragma unroll
  for (int r=0;r<4;r++){
    int n = nb + ty + r*8, k = kb + tx;
    if (n < N){
      float v = t[tx][ty+r*8];
      ushort h = f2bf_rne(v);
      float hf = __uint_as_float(((unsigned)h)<<16);
      ushort l = f2bf_rne(v - hf);
      size_t o = (size_t)(rowoff+n)*dld + koff + k;
      dh[o]=h; dl[o]=l;
    }
  }
}

// ---------------------------------------------------------------------------
// Row softmax (one wave/row) with zero-padded tail [cols, padto)
// ---------------------------------------------------------------------------
__global__ __launch_bounds__(64)
void softmax_kernel(const float* __restrict__ in, float* __restrict__ out,
                    int cols, int ldi, int ldo, int padto)
{
  int row = blockIdx.x, lane = threadIdx.x;
  const float* rp = in + (size_t)row*ldi;
  float m = -INFINITY;
  for (int c = lane; c < cols; c += 64) m = fmaxf(m, rp[c]);
  for (int off = 32; off; off >>= 1) m = fmaxf(m, __shfl_xor(m, off));
  float s = 0.f;
  for (int c = lane; c < cols; c += 64) s += expf(rp[c]-m);
  for (int off = 32; off; off >>= 1) s += __shfl_xor(s, off);
  float inv = 1.f/s;
  float* op = out + (size_t)row*ldo;
  for (int c = lane; c < padto; c += 64)
    op[c] = (c < cols) ? expf(rp[c]-m)*inv : 0.f;
}

__global__ __launch_bounds__(64)
void argmax_kernel(const float* __restrict__ ref, float* __restrict__ preds)
{
  int row = blockIdx.x, lane = threadIdx.x;
  const float* rp = ref + (size_t)row*NOc;
  float bv = -INFINITY; int bi = NOc;
  for (int c = 1+lane; c < NOc; c += 64) { float v = rp[c]; if (v > bv) { bv=v; bi=c; } }
  for (int off=32; off; off>>=1) {
    float ov = __shfl_xor(bv, off); int oi = __shfl_xor(bi, off);
    if (ov > bv || (ov == bv && oi < bi)) { bv = ov; bi = oi; }
  }
  if (lane==0) preds[row] = (float)bi;
}

// copy 512 cols within an ld-1024 buffer (dst/src are column bases)
__global__ __launch_bounds__(256)
void copy512(float* __restrict__ dst, const float* __restrict__ src, int M)
{
  int i = blockIdx.x*256+threadIdx.x;
  if (i >= M*128) return;
  int row=i>>7, hq=(i&127)<<2;
  *(float4*)&dst[(size_t)row*1024+hq] = *(const float4*)&src[(size_t)row*1024+hq];
}

// segment sums of hr (HX cols 0..511, ld 1024) into SumSO [512][1024]
// (cols 0..511 = subj-sum, 512..1023 = obj-sum). grid (8,4,8), block 64.
__global__ __launch_bounds__(64)
void segsum2(const float* __restrict__ HX, const int* __restrict__ rel_inds,
             float* __restrict__ SumSO)
{
  __shared__ float accS[64][64];
  __shared__ float accO[64][64];
  const int t = threadIdx.x;
  const int hb = blockIdx.x*64;
  const int img = blockIdx.z;
  const int relbase = img*Rn + blockIdx.y*(Rn/4);
  for (int ob=0; ob<64; ob++){ accS[ob][t]=0.f; accO[ob][t]=0.f; }
  for (int i=0;i<Rn/4;i++){
    int r = relbase+i;
    int s = rel_inds[r*3+1] - img*64;
    int o = rel_inds[r*3+2] - img*64;
    float v = HX[(size_t)r*1024 + hb + t];
    accS[s][t]+=v; accO[o][t]+=v;
  }
  for (int ob=0;ob<64;ob++){
    size_t rowb = (size_t)(img*64+ob)*1024 + hb + t;
    atomicAdd(&SumSO[rowb],     accS[ob][t]);
    atomicAdd(&SumSO[rowb+512], accO[ob][t]);
  }
}

// rel GRU stage A: z=sig(Gs_z[s]+Go_z[o]+hU_z+bz); RH=sig(...r...)*hr
__global__ __launch_bounds__(256)
void gru_rel_A2(const int* __restrict__ rel, const float* __restrict__ Gso,
                const float* __restrict__ hU, const float* __restrict__ HX,
                const float* __restrict__ bz, const float* __restrict__ br,
                float* __restrict__ Z, float* __restrict__ RH)
{
  int i = blockIdx.x*256 + threadIdx.x;
  if (i >= BRt*128) return;
  int r = i>>7, hq = (i&127)<<2;
  int s = rel[r*3+1], o = rel[r*3+2];
  float4 gzs = *(const float4*)&Gso[(size_t)s*3072 + hq];
  float4 gzo = *(const float4*)&Gso[(size_t)o*3072 + 1536 + hq];
  float4 grs = *(const float4*)&Gso[(size_t)s*3072 + 512 + hq];
  float4 gro = *(const float4*)&Gso[(size_t)o*3072 + 2048 + hq];
  float4 uz  = *(const float4*)&hU[(size_t)r*1024 + hq];
  float4 ur  = *(const float4*)&hU[(size_t)r*1024 + 512 + hq];
  float4 bzv = *(const float4*)&bz[hq];
  float4 brv = *(const float4*)&br[hq];
  float4 hv  = *(const float4*)&HX[(size_t)r*1024 + hq];
  float4 z, rh;
  z.x = sigmf(gzs.x+gzo.x+uz.x+bzv.x);
  z.y = sigmf(gzs.y+gzo.y+uz.y+bzv.y);
  z.z = sigmf(gzs.z+gzo.z+uz.z+bzv.z);
  z.w = sigmf(gzs.w+gzo.w+uz.w+bzv.w);
  rh.x = sigmf(grs.x+gro.x+ur.x+brv.x)*hv.x;
  rh.y = sigmf(grs.y+gro.y+ur.y+brv.y)*hv.y;
  rh.z = sigmf(grs.z+gro.z+ur.z+brv.z)*hv.z;
  rh.w = sigmf(grs.w+gro.w+ur.w+brv.w)*hv.w;
  *(float4*)&Z[(size_t)r*512+hq]  = z;
  *(float4*)&RH[(size_t)r*512+hq] = rh;
}

// rel GRU stage B: hr = (1-z)hr + z*tanh(Gs_h[s]+Go_h[o]+rhU+bh)
__global__ __launch_bounds__(256)
void gru_rel_B2(const int* __restrict__ rel, const float* __restrict__ Gso,
                const float* __restrict__ rhU, const float* __restrict__ Z,
                const float* __restrict__ bh, float* __restrict__ HX)
{
  int i = blockIdx.x*256 + threadIdx.x;
  if (i >= BRt*128) return;
  int r = i>>7, hq = (i&127)<<2;
  int s = rel[r*3+1], o = rel[r*3+2];
  float4 ghs = *(const float4*)&Gso[(size_t)s*3072 + 1024 + hq];
  float4 gho = *(const float4*)&Gso[(size_t)o*3072 + 2560 + hq];
  float4 ru  = *(const float4*)&rhU[(size_t)r*512 + hq];
  float4 bhv = *(const float4*)&bh[hq];
  float4 z   = *(const float4*)&Z[(size_t)r*512 + hq];
  float4 hv  = *(const float4*)&HX[(size_t)r*1024 + hq];
  float4 o4;
  o4.x = (1.f-z.x)*hv.x + z.x*tanhf(ghs.x+gho.x+ru.x+bhv.x);
  o4.y = (1.f-z.y)*hv.y + z.y*tanhf(ghs.y+gho.y+ru.y+bhv.y);
  o4.z = (1.f-z.z)*hv.z + z.z*tanhf(ghs.z+gho.z+ru.z+bhv.z);
  o4.w = (1.f-z.w)*hv.w + z.w*tanhf(ghs.w+gho.w+ru.w+bhv.w);
  *(float4*)&HX[(size_t)r*1024+hq] = o4;
}

// obj gates: z=sig(G1_z+G2_z+bz), RHo=sig(G1_r+G2_r+br)*ho
__global__ __launch_bounds__(256)
void obj_gate(const float* __restrict__ G1, const float* __restrict__ G2,
              const float* __restrict__ HOX, const float* __restrict__ bz,
              const float* __restrict__ br, float* __restrict__ Zo,
              float* __restrict__ RHo)
{
  int i = blockIdx.x*256 + threadIdx.x;
  if (i >= BNt*128) return;
  int row = i>>7, hq = (i&127)<<2;
  float4 g1z = *(const float4*)&G1[(size_t)row*1536 + hq];
  float4 g2z = *(const float4*)&G2[(size_t)row*1024 + hq];
  float4 g1r = *(const float4*)&G1[(size_t)row*1536 + 512 + hq];
  float4 g2r = *(const float4*)&G2[(size_t)row*1024 + 512 + hq];
  float4 bzv = *(const float4*)&bz[hq];
  float4 brv = *(const float4*)&br[hq];
  float4 hv  = *(const float4*)&HOX[(size_t)row*1024 + hq];
  float4 z, rh;
  z.x = sigmf(g1z.x+g2z.x+bzv.x); z.y = sigmf(g1z.y+g2z.y+bzv.y);
  z.z = sigmf(g1z.z+g2z.z+bzv.z); z.w = sigmf(g1z.w+g2z.w+bzv.w);
  rh.x = sigmf(g1r.x+g2r.x+brv.x)*hv.x;
  rh.y = sigmf(g1r.y+g2r.y+brv.y)*hv.y;
  rh.z = sigmf(g1r.z+g2r.z+brv.z)*hv.z;
  rh.w = sigmf(g1r.w+g2r.w+brv.w)*hv.w;
  *(float4*)&Zo[(size_t)row*512+hq]  = z;
  *(float4*)&RHo[(size_t)row*512+hq] = rh;
}

__global__ __launch_bounds__(256)
void obj_upd(const float* __restrict__ G1, const float* __restrict__ rhUo,
             const float* __restrict__ Zo, const float* __restrict__ bh,
             float* __restrict__ HOX)
{
  int i = blockIdx.x*256 + threadIdx.x;
  if (i >= BNt*128) return;
  int row = i>>7, hq = (i&127)<<2;
  float4 g1h = *(const float4*)&G1[(size_t)row*1536 + 1024 + hq];
  float4 ru  = *(const float4*)&rhUo[(size_t)row*512 + hq];
  float4 z   = *(const float4*)&Zo[(size_t)row*512 + hq];
  float4 bhv = *(const float4*)&bh[hq];
  float4 hv  = *(const float4*)&HOX[(size_t)row*1024 + hq];
  float4 o4;
  o4.x = (1.f-z.x)*hv.x + z.x*tanhf(g1h.x+ru.x+bhv.x);
  o4.y = (1.f-z.y)*hv.y + z.y*tanhf(g1h.y+ru.y+bhv.y);
  o4.z = (1.f-z.z)*hv.z + z.z*tanhf(g1h.z+ru.z+bhv.z);
  o4.w = (1.f-z.w)*hv.w + z.w*tanhf(g1h.w+ru.w+bhv.w);
  *(float4*)&HOX[(size_t)row*1024+hq] = o4;
}

// ---------------------------------------------------------------------------
// Host wrappers
// ---------------------------------------------------------------------------
static void G128(hipStream_t s,const float*A,const ushort*bh,const ushort*bl,float*C,
  int M,int N,int K,int lda,int ldb,int ldc,const float*bias,int beta,int act){
  dim3 g((N+127)/128,(M+127)/128);
  gemm_b3<128,128><<<g,256,0,s>>>(A,bh,bl,C,M,N,K,lda,ldb,ldc,bias,beta,act);
}
static void G64(hipStream_t s,const float*A,const ushort*bh,const ushort*bl,float*C,
  int M,int N,int K,int lda,int ldb,int ldc,const float*bias,int beta,int act){
  dim3 g((N+63)/64,(M+63)/64);
  gemm_b3<64,64><<<g,256,0,s>>>(A,bh,bl,C,M,N,K,lda,ldb,ldc,bias,beta,act);
}
static void G128x64(hipStream_t s,const float*A,const ushort*bh,const ushort*bl,float*C,
  int M,int N,int K,int lda,int ldb,int ldc,const float*bias,int beta,int act){
  dim3 g((N+63)/64,(M+127)/128);
  gemm_b3<128,64><<<g,256,0,s>>>(A,bh,bl,C,M,N,K,lda,ldb,ldc,bias,beta,act);
}
static void TS(hipStream_t s,const float*src,int K,int N,ushort*dh,ushort*dl,
               int dld,int rowoff,int koff,int Kpad){
  dim3 g(Kpad/32,(N+31)/32);
  tsplit<<<g,dim3(32,8),0,s>>>(src,K,N,dh,dl,dld,rowoff,koff);
}

extern "C" void kernel_launch(void* const* d_in, const int* in_sizes, int n_in,
                              void* d_out, int out_size, void* d_ws, size_t ws_size,
                              hipStream_t stream) {
  (void)in_sizes; (void)n_in; (void)out_size; (void)ws_size;
  const int*   rel_inds   = (const int*)  d_in[1];
  const float* obj_fmaps  = (const float*)d_in[2];
  const float* obj_logits = (const float*)d_in[3];
  const float* vr         = (const float*)d_in[4];
  const float* W_obj      = (const float*)d_in[5];
  const float* b_obj      = (const float*)d_in[6];
  const float* W_rel      = (const float*)d_in[7];
  const float* b_rel      = (const float*)d_in[8];
  const float* W_prob     = (const float*)d_in[9];
  const float* b_prob     = (const float*)d_in[10];
  const float* W_so       = (const float*)d_in[11];
  const float* W_oo       = (const float*)d_in[12];
  const float* W_rs       = (const float*)d_in[13];
  const float* W_ro       = (const float*)d_in[14];
  const float* Wz         = (const float*)d_in[15];
  const float* Uz         = (const float*)d_in[16];
  const float* bz         = (const float*)d_in[17];
  const float* Wr         = (const float*)d_in[18];
  const float* Ur         = (const float*)d_in[19];
  const float* br         = (const float*)d_in[20];
  const float* Wh         = (const float*)d_in[21];
  const float* Uh         = (const float*)d_in[22];
  const float* bh         = (const float*)d_in[23];
  const float* W_out_rel  = (const float*)d_in[24];
  const float* b_out_rel  = (const float*)d_in[25];
  const float* W_cls_rel  = (const float*)d_in[26];
  const float* b_cls_rel  = (const float*)d_in[27];
  const float* W_out_obj  = (const float*)d_in[28];
  const float* b_out_obj  = (const float*)d_in[29];
  const float* W_cls_obj  = (const float*)d_in[30];
  const float* b_cls_obj  = (const float*)d_in[31];

  // output layout (floats): obj_ref | obj_preds | rel_logits | scpred | scent
  float* out          = (float*)d_out;
  float* out_obj_ref  = out;
  float* out_preds    = out + 77312;
  float* out_rel_log  = out + 77824;
  float* out_scpred   = out + 913408;
  float* out_scent    = out + 1748992;

  // ---- workspace carve ----
  char* base = (char*)d_ws; size_t off = 0;
  auto alloc = [&](size_t bytes)->void*{ void* p = base+off; off = (off+bytes+255)&~(size_t)255; return p; };
  float*  HX    = (float*) alloc((size_t)BRt*1024*4);  // hr | xr
  float*  hU    = (float*) alloc((size_t)BRt*1024*4);  // also rhU / Crel
  float*  Zb    = (float*) alloc((size_t)BRt*512*4);   // also setup Bt scratch
  float*  RH    = (float*) alloc((size_t)BRt*512*4);   // also Wcat fp32 scratch
  ushort* Bt3h  = (ushort*)alloc((size_t)1536*512*2);  // [Wz|Wr|Wh]^T
  ushort* Bt3l  = (ushort*)alloc((size_t)1536*512*2);
  ushort* BtUh2 = (ushort*)alloc((size_t)1024*512*2);  // [Uz|Ur]^T
  ushort* BtUl2 = (ushort*)alloc((size_t)1024*512*2);
  ushort* BtUhh = (ushort*)alloc((size_t)512*512*2);   // Uh^T
  ushort* BtUhl = (ushort*)alloc((size_t)512*512*2);
  ushort* BtRRh = (ushort*)alloc((size_t)512*1024*2);  // [W_rs;W_ro]^T (K=1024)
  ushort* BtRRl = (ushort*)alloc((size_t)512*1024*2);
  ushort* BtORh = (ushort*)alloc((size_t)512*1024*2);  // W_out_rel^T
  ushort* BtORl = (ushort*)alloc((size_t)512*1024*2);
  ushort* BtCRh = (ushort*)alloc((size_t)51*512*2);    // W_cls_rel^T
  ushort* BtCRl = (ushort*)alloc((size_t)51*512*2);
  ushort* BtOOh = (ushort*)alloc((size_t)512*1024*2);  // W_out_obj^T
  ushort* BtOOl = (ushort*)alloc((size_t)512*1024*2);
  ushort* BtCOh = (ushort*)alloc((size_t)151*512*2);   // W_cls_obj^T
  ushort* BtCOl = (ushort*)alloc((size_t)151*512*2);
  ushort* BtWCh = (ushort*)alloc((size_t)3072*512*2);  // Wcat^T = [Wso@cat3|Woo@cat3]^T
  ushort* BtWCl = (ushort*)alloc((size_t)3072*512*2);
  float*  Gso   = (float*) alloc((size_t)512*3072*4);
  float*  G1    = (float*) alloc((size_t)512*1536*4);
  float*  G2    = (float*) alloc((size_t)512*1024*4);
  float*  SumSO = (float*) alloc((size_t)512*1024*4);
  float*  mo    = (float*) alloc((size_t)512*512*4);
  float*  Zo    = (float*) alloc((size_t)512*512*4);
  float*  RHo   = (float*) alloc((size_t)512*512*4);
  float*  rhUo  = (float*) alloc((size_t)512*512*4);
  float*  HOX   = (float*) alloc((size_t)512*1024*4); // ho | xo
  float*  oprob = (float*) alloc((size_t)512*152*4);
  float*  Cobj  = (float*) alloc((size_t)512*512*4);

  // setup-only aliases (consumed before first use of Zb/RH)
  ushort* BtRELh = (ushort*)Zb;                        // W_rel^T  [512][4096]
  ushort* BtRELl = BtRELh + (size_t)512*4096;
  ushort* BtOBJh = BtRELl + (size_t)512*4096;          // W_obj^T
  ushort* BtOBJl = BtOBJh + (size_t)512*4096;
  ushort* BtPRh  = BtOBJl + (size_t)512*4096;          // W_prob^T [512][160]
  ushort* BtPRl  = BtPRh  + (size_t)512*160;
  float*  Wcat   = RH;                                 // fp32 [512][3072]

  // ---- setup ----
  softmax_kernel<<<512,64,0,stream>>>(obj_logits, oprob, NOc, NOc, 152, 152);
  TS(stream, W_rel,  4096,512, BtRELh,BtRELl, 4096, 0,0, 4096);
  TS(stream, W_obj,  4096,512, BtOBJh,BtOBJl, 4096, 0,0, 4096);
  TS(stream, W_prob,  151,512, BtPRh, BtPRl,   160, 0,0,  160);
  TS(stream, Wz, 512,512, Bt3h,Bt3l, 512,    0,0, 512);
  TS(stream, Wr, 512,512, Bt3h,Bt3l, 512,  512,0, 512);
  TS(stream, Wh, 512,512, Bt3h,Bt3l, 512, 1024,0, 512);
  TS(stream, Uz, 512,512, BtUh2,BtUl2, 512,   0,0, 512);
  TS(stream, Ur, 512,512, BtUh2,BtUl2, 512, 512,0, 512);
  TS(stream, Uh, 512,512, BtUhh,BtUhl, 512, 0,0, 512);
  TS(stream, W_rs, 512,512, BtRRh,BtRRl, 1024, 0,  0, 512);
  TS(stream, W_ro, 512,512, BtRRh,BtRRl, 1024, 0,512, 512);
  TS(stream, W_out_rel, 1024,512, BtORh,BtORl, 1024, 0,0, 1024);
  TS(stream, W_cls_rel,  512, 51, BtCRh,BtCRl,  512, 0,0,  512);
  TS(stream, W_out_obj, 1024,512, BtOOh,BtOOl, 1024, 0,0, 1024);
  TS(stream, W_cls_obj,  512,151, BtCOh,BtCOl,  512, 0,0,  512);
  // xo -> HOX cols 512..1023
  G64(stream, obj_fmaps, BtOBJh,BtOBJl, HOX+512, 512,512,4096, 4096,4096,1024, b_obj,0,0);
  G64(stream, oprob,     BtPRh, BtPRl,  HOX+512, 512,512, 151,  152, 160,1024, b_prob,1,0);
  // xr -> HX cols 512..1023
  G128(stream, vr, BtRELh,BtRELl, HX+512, BRt,512,4096, 4096,4096,1024, b_rel,0,0);
  copy512<<<(BRt*128+255)/256,256,0,stream>>>(HX, HX+512, BRt);
  copy512<<<(512*128+255)/256,256,0,stream>>>(HOX, HOX+512, 512);
  // Wcat = [W_so@cat3 | W_oo@cat3], then transpose-split
  G64(stream, W_so, Bt3h,Bt3l, Wcat,      512,1536,512, 512,512,3072, nullptr,0,0);
  G64(stream, W_oo, Bt3h,Bt3l, Wcat+1536, 512,1536,512, 512,512,3072, nullptr,0,0);
  TS(stream, Wcat, 512,3072, BtWCh,BtWCl, 512, 0,0, 512);

  // ---- T GGNN steps ----
  for (int t = 0; t < Tt; t++) {
    // Gso = ho @ [WsoW | WooW]  (old ho)
    G64(stream, HOX, BtWCh,BtWCl, Gso, 512,3072,512, 1024,512,3072, nullptr,0,0);
    // segment sums of old hr
    hipMemsetAsync(SumSO, 0, (size_t)512*1024*4, stream);
    segsum2<<<dim3(8,4,8),64,0,stream>>>(HX, rel_inds, SumSO);
    // hU = hr @ [Uz|Ur]
    G128(stream, HX, BtUh2,BtUl2, hU, BRt,1024,512, 1024,512,1024, nullptr,0,0);
    // rel GRU
    gru_rel_A2<<<(BRt*128+255)/256,256,0,stream>>>(rel_inds, Gso, hU, HX, bz, br, Zb, RH);
    G128(stream, RH, BtUhh,BtUhl, hU /*rhU ld512*/, BRt,512,512, 512,512,512, nullptr,0,0);
    gru_rel_B2<<<(BRt*128+255)/256,256,0,stream>>>(rel_inds, Gso, hU, Zb, bh, HX);
    // obj GRU
    G64(stream, SumSO, BtRRh,BtRRl, mo, 512,512,1024, 1024,1024,512, nullptr,0,0);
    G64(stream, mo,  Bt3h,Bt3l,   G1, 512,1536,512,  512,512,1536, nullptr,0,0);
    G64(stream, HOX, BtUh2,BtUl2, G2, 512,1024,512, 1024,512,1024, nullptr,0,0);
    obj_gate<<<(512*128+255)/256,256,0,stream>>>(G1,G2,HOX,bz,br,Zo,RHo);
    G64(stream, RHo, BtUhh,BtUhl, rhUo, 512,512,512, 512,512,512, nullptr,0,0);
    obj_upd<<<(512*128+255)/256,256,0,stream>>>(G1, rhUo, Zo, bh, HOX);
  }

  // ---- heads ----
  float* Crel = hU;
  G128(stream, HX, BtORh,BtORl, Crel, BRt,512,1024, 1024,1024,512, b_out_rel,0,2);
  G128x64(stream, Crel, BtCRh,BtCRl, out_rel_log, BRt,NRc,512, 512,512,NRc, b_cls_rel,0,0);
  softmax_kernel<<<BRt,64,0,stream>>>(out_rel_log, out_scpred, NRc, NRc, NRc, NRc);
  G64(stream, HOX, BtOOh,BtOOl, Cobj, 512,512,1024, 1024,1024,512, b_out_obj,0,2);
  G64(stream, Cobj, BtCOh,BtCOl, out_obj_ref, 512,NOc,512, 512,512,NOc, b_cls_obj,0,0);
  softmax_kernel<<<512,64,0,stream>>>(out_obj_ref, out_scent, NOc, NOc, NOc, NOc);
  argmax_kernel<<<512,64,0,stream>>>(out_obj_ref, out_preds);
}

// Round 3
// 2287.948 us; speedup vs baseline: 2.0215x; 1.0033x over previous
//
#include <hip/hip_runtime.h>
#include <math.h>

// Problem constants
#define Bn   8
#define Nn   64
#define Rn   2048
#define Dn   4096
#define Hn   512
#define NOc  151
#define NRc  51
#define Tt   3
#define BNt  (Bn*Nn)   // 512 objects
#define BRt  (Bn*Rn)   // 16384 relations
#define Mall (BRt+BNt) // 16896 = rel rows + appended obj rows

typedef __attribute__((ext_vector_type(8))) short short8;
typedef __attribute__((ext_vector_type(4))) float f32x4;

__device__ __forceinline__ float sigmf(float x){ return 1.0f/(1.0f+expf(-x)); }

__device__ __forceinline__ ushort f2bf_rne(float x){
  unsigned u = __float_as_uint(x);
  unsigned r = u + 0x7FFFu + ((u>>16)&1u);
  return (ushort)(r>>16);
}

// ---------------------------------------------------------------------------
// bf16x3 MFMA GEMM, software-pipelined (register prefetch of next K-tile).
// B pre-split bf16 hi/lo planes, [N][Kld] layout, k-padded to 32 with zeros.
// A fp32, split to bf16 hi/lo in-kernel. C = Ah*Bh + Ah*Bl + Al*Bh (fp32 acc).
// mode 0: C = act(acc (+beta*C) (+bias)); optional dup store at gn+dupoff.
// mode 1 (GATE): rel/obj GRU z & r gates -> Zbuf, RHbuf (N must be 1024).
// mode 2 (UPD):  rel/obj GRU h-candidate + state update of HXbuf (N=512).
// ---------------------------------------------------------------------------
template<int BM,int BN>
__global__ __launch_bounds__(256)
void gemm_b3(const float* __restrict__ A, const ushort* __restrict__ Bhg,
             const ushort* __restrict__ Blg, float* __restrict__ C,
             int M,int N,int K,int lda,int ldb,int ldc,
             const float* __restrict__ bias, const float* __restrict__ bias2,
             int beta,int act,int dupoff,
             int mode, const int* __restrict__ rel,
             const float* __restrict__ Gso, const float* __restrict__ G1,
             int brt, float* __restrict__ Zbuf, float* __restrict__ RHbuf,
             float* __restrict__ HXbuf)
{
  constexpr int MT = BM/32, NT = BN/32;
  __shared__ ushort Ah[BM*40], Al[BM*40], Bh[BN*40], Bl[BN*40];
  const int tid  = threadIdx.x;
  const int lane = tid & 63;
  const int wid  = tid >> 6;
  const int quad = lane >> 4, l15 = lane & 15;
  const int wm = (wid>>1)*(BM/2), wn = (wid&1)*(BN/2);
  const int bm = blockIdx.y*BM, bn = blockIdx.x*BN;

  constexpr int TPR  = 256/BM;      // threads per A row
  constexpr int FPT  = 32/TPR;      // floats per thread (A)
  const int ar = tid / TPR;
  const int ak = (tid % TPR) * FPT;
  constexpr int TPRB = 256/BN;
  constexpr int SPT  = 32/TPRB;     // shorts per thread per B plane
  const int br_ = tid / TPRB;
  const int bk = (tid % TPRB) * SPT;
  const int grA = bm + ar;
  const int grB = bn + br_;
  const bool avec = ((lda&3)==0);

  f32x4 acc[MT][NT];
#pragma unroll
  for (int i=0;i<MT;i++)
#pragma unroll
    for (int j=0;j<NT;j++) acc[i][j] = (f32x4){0.f,0.f,0.f,0.f};

  float av[FPT];
  short8 bvh[SPT/8], bvl[SPT/8];

  auto load_tile = [&](int k0){
    if (grA < M && avec && k0 + ak + FPT <= K) {
      const float* p = A + (size_t)grA*lda + k0 + ak;
#pragma unroll
      for (int i=0;i<FPT/4;i++) ((float4*)av)[i] = ((const float4*)p)[i];
    } else {
#pragma unroll
      for (int i=0;i<FPT;i++){
        int gk = k0+ak+i;
        av[i] = (grA<M && gk<K) ? A[(size_t)grA*lda+gk] : 0.f;
      }
    }
    if (grB < N){
#pragma unroll
      for (int i=0;i<SPT/8;i++){
        bvh[i] = *(const short8*)(Bhg + (size_t)grB*ldb + k0 + bk + i*8);
        bvl[i] = *(const short8*)(Blg + (size_t)grB*ldb + k0 + bk + i*8);
      }
    } else {
#pragma unroll
      for (int i=0;i<SPT/8;i++){
#pragma unroll
        for (int q=0;q<8;q++){ bvh[i][q]=0; bvl[i][q]=0; }
      }
    }
  };

  load_tile(0);

  for (int k0=0; k0<K; k0+=32) {
    // ---- stage registers -> LDS (A converted fp32 -> bf16 hi/lo) ----
    {
      ushort hs[FPT], ls[FPT];
#pragma unroll
      for (int i=0;i<FPT;i++){
        ushort h = f2bf_rne(av[i]);
        float hf = __uint_as_float(((unsigned)h)<<16);
        hs[i]=h; ls[i]=f2bf_rne(av[i]-hf);
      }
#pragma unroll
      for (int i=0;i<FPT;i+=8){
        short8 vh, vl;
#pragma unroll
        for (int q=0;q<8;q++){ vh[q]=(short)hs[i+q]; vl[q]=(short)ls[i+q]; }
        *(short8*)&Ah[ar*40+ak+i] = vh;
        *(short8*)&Al[ar*40+ak+i] = vl;
      }
#pragma unroll
      for (int i=0;i<SPT/8;i++){
        *(short8*)&Bh[br_*40+bk+i*8] = bvh[i];
        *(short8*)&Bl[br_*40+bk+i*8] = bvl[i];
      }
    }
    __syncthreads();
    // ---- prefetch next tile (overlaps MFMA below) ----
    if (k0+32 < K) load_tile(k0+32);
    // ---- fragments + MFMA ----
    {
      short8 afh[MT], afl[MT], bfh[NT], bfl[NT];
#pragma unroll
      for (int i=0;i<MT;i++){
        int o = (wm + i*16 + l15)*40 + quad*8;
        afh[i] = *(const short8*)&Ah[o];
        afl[i] = *(const short8*)&Al[o];
      }
#pragma unroll
      for (int j=0;j<NT;j++){
        int o = (wn + j*16 + l15)*40 + quad*8;
        bfh[j] = *(const short8*)&Bh[o];
        bfl[j] = *(const short8*)&Bl[o];
      }
#pragma unroll
      for (int i=0;i<MT;i++)
#pragma unroll
        for (int j=0;j<NT;j++)
          acc[i][j] = __builtin_amdgcn_mfma_f32_16x16x32_bf16(afh[i], bfh[j], acc[i][j], 0,0,0);
#pragma unroll
      for (int i=0;i<MT;i++)
#pragma unroll
        for (int j=0;j<NT;j++)
          acc[i][j] = __builtin_amdgcn_mfma_f32_16x16x32_bf16(afh[i], bfl[j], acc[i][j], 0,0,0);
#pragma unroll
      for (int i=0;i<MT;i++)
#pragma unroll
        for (int j=0;j<NT;j++)
          acc[i][j] = __builtin_amdgcn_mfma_f32_16x16x32_bf16(afl[i], bfh[j], acc[i][j], 0,0,0);
    }
    __syncthreads();
  }

  // ---- epilogue: C/D layout col=lane&15, row=quad*4+reg ----
  if (mode == 0) {
#pragma unroll
    for (int i=0;i<MT;i++){
      int gm0 = bm + wm + i*16 + quad*4;
#pragma unroll
      for (int j=0;j<NT;j++){
        int gn = bn + wn + j*16 + l15;
        if (gn >= N) continue;
#pragma unroll
        for (int r=0;r<4;r++){
          int gm = gm0 + r;
          if (gm >= M) continue;
          float v = acc[i][j][r];
          if (beta) v += C[(size_t)gm*ldc+gn];
          if (bias) v += bias[gn];
          if (act==1) v = sigmf(v);
          else if (act==2) v = tanhf(v);
          C[(size_t)gm*ldc+gn] = v;
          if (dupoff) C[(size_t)gm*ldc+gn+dupoff] = v;
        }
      }
    }
  } else if (mode == 1) {   // GATE: z -> Zbuf (gn<512), r*h -> RHbuf (gn>=512)
#pragma unroll
    for (int i=0;i<MT;i++){
#pragma unroll
      for (int r=0;r<4;r++){
        int gm = bm + wm + i*16 + quad*4 + r;
        if (gm >= M) continue;
        bool isrel = gm < brt;
        int s=0,o=0; const float* g1row = nullptr;
        if (isrel){ s = rel[gm*3+1]; o = rel[gm*3+2]; }
        else g1row = G1 + (size_t)(gm-brt)*1536;
#pragma unroll
        for (int j=0;j<NT;j++){
          int gn = bn + wn + j*16 + l15;
          float v = acc[i][j][r];
          if (gn < 512){
            float g = isrel ? Gso[(size_t)s*3072+gn] + Gso[(size_t)o*3072+1536+gn]
                            : g1row[gn];
            Zbuf[(size_t)gm*512+gn] = sigmf(v + g + bias[gn]);
          } else {
            int h = gn - 512;
            float g = isrel ? Gso[(size_t)s*3072+512+h] + Gso[(size_t)o*3072+2048+h]
                            : g1row[512+h];
            RHbuf[(size_t)gm*512+h] = sigmf(v + g + bias2[h]) * HXbuf[(size_t)gm*1024+h];
          }
        }
      }
    }
  } else {                  // UPD: h-candidate + GRU state update in HXbuf
#pragma unroll
    for (int i=0;i<MT;i++){
#pragma unroll
      for (int r=0;r<4;r++){
        int gm = bm + wm + i*16 + quad*4 + r;
        if (gm >= M) continue;
        bool isrel = gm < brt;
        int s=0,o=0; const float* g1row = nullptr;
        if (isrel){ s = rel[gm*3+1]; o = rel[gm*3+2]; }
        else g1row = G1 + (size_t)(gm-brt)*1536;
#pragma unroll
        for (int j=0;j<NT;j++){
          int h = bn + wn + j*16 + l15;
          float v = acc[i][j][r];
          float g = isrel ? Gso[(size_t)s*3072+1024+h] + Gso[(size_t)o*3072+2560+h]
                          : g1row[1024+h];
          float hh = tanhf(v + g + bias[h]);
          float z = Zbuf[(size_t)gm*512+h];
          size_t hx = (size_t)gm*1024+h;
          HXbuf[hx] = (1.f-z)*HXbuf[hx] + z*hh;
        }
      }
    }
  }
}

// ---------------------------------------------------------------------------
// Transpose+split weight: src fp32 [K][N] (ld N) -> dh/dl bf16 [rowoff+n][koff+k]
// (ld dld). k >= K (up to gridDim.x*32) written as zero (K-padding).
// ---------------------------------------------------------------------------
__global__ __launch_bounds__(256)
void tsplit(const float* __restrict__ src,int K,int N,
            ushort* __restrict__ dh, ushort* __restrict__ dl,
            int dld,int rowoff,int koff)
{
  __shared__ float t[32][33];
  const int tx = threadIdx.x, ty = threadIdx.y;
  const int kb = blockIdx.x*32, nb = blockIdx.y*32;
#pragma unroll
  for (int r=0;r<4;r++){
    int k = kb + ty + r*8, n = nb + tx;
    t[ty+r*8][tx] = (k<K && n<N) ? src[(size_t)k*N + n] : 0.f;
  }
  __syncthreads();
#pragma unroll
  for (int r=0;r<4;r++){
    int n = nb + ty + r*8, k = kb + tx;
    if (n < N){
      float v = t[tx][ty+r*8];
      ushort h = f2bf_rne(v);
      float hf = __uint_as_float(((unsigned)h)<<16);
      ushort l = f2bf_rne(v - hf);
      size_t o = (size_t)(rowoff+n)*dld + koff + k;
      dh[o]=h; dl[o]=l;
    }
  }
}

// ---------------------------------------------------------------------------
__global__ __launch_bounds__(64)
void softmax_kernel(const float* __restrict__ in, float* __restrict__ out,
                    int cols, int ldi, int ldo, int padto)
{
  int row = blockIdx.x, lane = threadIdx.x;
  const float* rp = in + (size_t)row*ldi;
  float m = -INFINITY;
  for (int c = lane; c < cols; c += 64) m = fmaxf(m, rp[c]);
  for (int off = 32; off; off >>= 1) m = fmaxf(m, __shfl_xor(m, off));
  float s = 0.f;
  for (int c = lane; c < cols; c += 64) s += expf(rp[c]-m);
  for (int off = 32; off; off >>= 1) s += __shfl_xor(s, off);
  float inv = 1.f/s;
  float* op = out + (size_t)row*ldo;
  for (int c = lane; c < padto; c += 64)
    op[c] = (c < cols) ? expf(rp[c]-m)*inv : 0.f;
}

__global__ __launch_bounds__(64)
void argmax_kernel(const float* __restrict__ ref, float* __restrict__ preds)
{
  int row = blockIdx.x, lane = threadIdx.x;
  const float* rp = ref + (size_t)row*NOc;
  float bv = -INFINITY; int bi = NOc;
  for (int c = 1+lane; c < NOc; c += 64) { float v = rp[c]; if (v > bv) { bv=v; bi=c; } }
  for (int off=32; off; off>>=1) {
    float ov = __shfl_xor(bv, off); int oi = __shfl_xor(bi, off);
    if (ov > bv || (ov == bv && oi < bi)) { bv = ov; bi = oi; }
  }
  if (lane==0) preds[row] = (float)bi;
}

// segment sums of hr (HX cols 0..511, ld 1024) into SumSO [512][1024]
// (cols 0..511 = subj-sum, 512..1023 = obj-sum). grid (8,4,8), block 64.
__global__ __launch_bounds__(64)
void segsum2(const float* __restrict__ HX, const int* __restrict__ rel_inds,
             float* __restrict__ SumSO)
{
  __shared__ float accS[64][64];
  __shared__ float accO[64][64];
  const int t = threadIdx.x;
  const int hb = blockIdx.x*64;
  const int img = blockIdx.z;
  const int relbase = img*Rn + blockIdx.y*(Rn/4);
  for (int ob=0; ob<64; ob++){ accS[ob][t]=0.f; accO[ob][t]=0.f; }
  for (int i=0;i<Rn/4;i++){
    int r = relbase+i;
    int s = rel_inds[r*3+1] - img*64;
    int o = rel_inds[r*3+2] - img*64;
    float v = HX[(size_t)r*1024 + hb + t];
    accS[s][t]+=v; accO[o][t]+=v;
  }
  for (int ob=0;ob<64;ob++){
    size_t rowb = (size_t)(img*64+ob)*1024 + hb + t;
    atomicAdd(&SumSO[rowb],     accS[ob][t]);
    atomicAdd(&SumSO[rowb+512], accO[ob][t]);
  }
}

// ---------------------------------------------------------------------------
// Host wrappers
// ---------------------------------------------------------------------------
#define NOFUSE 0,nullptr,nullptr,nullptr,0,nullptr,nullptr,nullptr
static void Gstd128(hipStream_t s,const float*A,const ushort*bh,const ushort*bl,float*C,
  int M,int N,int K,int lda,int ldb,int ldc,const float*bias,int beta,int act,int dupoff){
  dim3 g((N+127)/128,(M+127)/128);
  gemm_b3<128,128><<<g,256,0,s>>>(A,bh,bl,C,M,N,K,lda,ldb,ldc,bias,nullptr,beta,act,dupoff,NOFUSE);
}
static void Gstd64(hipStream_t s,const float*A,const ushort*bh,const ushort*bl,float*C,
  int M,int N,int K,int lda,int ldb,int ldc,const float*bias,int beta,int act,int dupoff){
  dim3 g((N+63)/64,(M+63)/64);
  gemm_b3<64,64><<<g,256,0,s>>>(A,bh,bl,C,M,N,K,lda,ldb,ldc,bias,nullptr,beta,act,dupoff,NOFUSE);
}
static void Gstd128x64(hipStream_t s,const float*A,const ushort*bh,const ushort*bl,float*C,
  int M,int N,int K,int lda,int ldb,int ldc,const float*bias,int beta,int act,int dupoff){
  dim3 g((N+63)/64,(M+127)/128);
  gemm_b3<128,64><<<g,256,0,s>>>(A,bh,bl,C,M,N,K,lda,ldb,ldc,bias,nullptr,beta,act,dupoff,NOFUSE);
}
static void TS(hipStream_t s,const float*src,int K,int N,ushort*dh,ushort*dl,
               int dld,int rowoff,int koff,int Kpad){
  dim3 g(Kpad/32,(N+31)/32);
  tsplit<<<g,dim3(32,8),0,s>>>(src,K,N,dh,dl,dld,rowoff,koff);
}

extern "C" void kernel_launch(void* const* d_in, const int* in_sizes, int n_in,
                              void* d_out, int out_size, void* d_ws, size_t ws_size,
                              hipStream_t stream) {
  (void)in_sizes; (void)n_in; (void)out_size; (void)ws_size;
  const int*   rel_inds   = (const int*)  d_in[1];
  const float* obj_fmaps  = (const float*)d_in[2];
  const float* obj_logits = (const float*)d_in[3];
  const float* vr         = (const float*)d_in[4];
  const float* W_obj      = (const float*)d_in[5];
  const float* b_obj      = (const float*)d_in[6];
  const float* W_rel      = (const float*)d_in[7];
  const float* b_rel      = (const float*)d_in[8];
  const float* W_prob     = (const float*)d_in[9];
  const float* b_prob     = (const float*)d_in[10];
  const float* W_so       = (const float*)d_in[11];
  const float* W_oo       = (const float*)d_in[12];
  const float* W_rs       = (const float*)d_in[13];
  const float* W_ro       = (const float*)d_in[14];
  const float* Wz         = (const float*)d_in[15];
  const float* Uz         = (const float*)d_in[16];
  const float* bz         = (const float*)d_in[17];
  const float* Wr         = (const float*)d_in[18];
  const float* Ur         = (const float*)d_in[19];
  const float* br         = (const float*)d_in[20];
  const float* Wh         = (const float*)d_in[21];
  const float* Uh         = (const float*)d_in[22];
  const float* bh         = (const float*)d_in[23];
  const float* W_out_rel  = (const float*)d_in[24];
  const float* b_out_rel  = (const float*)d_in[25];
  const float* W_cls_rel  = (const float*)d_in[26];
  const float* b_cls_rel  = (const float*)d_in[27];
  const float* W_out_obj  = (const float*)d_in[28];
  const float* b_out_obj  = (const float*)d_in[29];
  const float* W_cls_obj  = (const float*)d_in[30];
  const float* b_cls_obj  = (const float*)d_in[31];

  // output layout (floats): obj_ref | obj_preds | rel_logits | scpred | scent
  float* out          = (float*)d_out;
  float* out_obj_ref  = out;
  float* out_preds    = out + 77312;
  float* out_rel_log  = out + 77824;
  float* out_scpred   = out + 913408;
  float* out_scent    = out + 1748992;

  // ---- workspace carve ----
  char* base = (char*)d_ws; size_t off = 0;
  auto alloc = [&](size_t bytes)->void*{ void* p = base+off; off = (off+bytes+255)&~(size_t)255; return p; };
  float*  HX    = (float*) alloc((size_t)Mall*1024*4);  // [hr|xr] rel rows, [ho|xo] obj rows
  float*  Zb    = (float*) alloc((size_t)Mall*512*4);   // z gate; also setup Bt scratch; also Crel
  float*  RH    = (float*) alloc((size_t)Mall*512*4);   // r*h;    also Wcat/P fp32 scratch
  ushort* Bt3h  = (ushort*)alloc((size_t)1536*512*2);   // [Wz|Wr|Wh]^T
  ushort* Bt3l  = (ushort*)alloc((size_t)1536*512*2);
  ushort* BtU2h = (ushort*)alloc((size_t)1024*512*2);   // [Uz|Ur]^T
  ushort* BtU2l = (ushort*)alloc((size_t)1024*512*2);
  ushort* BtUHh = (ushort*)alloc((size_t)512*512*2);    // Uh^T
  ushort* BtUHl = (ushort*)alloc((size_t)512*512*2);
  ushort* BtPh  = (ushort*)alloc((size_t)1536*1024*2);  // ([W_rs;W_ro]@cat3)^T
  ushort* BtPl  = (ushort*)alloc((size_t)1536*1024*2);
  ushort* BtORh = (ushort*)alloc((size_t)512*1024*2);   // W_out_rel^T
  ushort* BtORl = (ushort*)alloc((size_t)512*1024*2);
  ushort* BtCRh = (ushort*)alloc((size_t)51*512*2);     // W_cls_rel^T
  ushort* BtCRl = (ushort*)alloc((size_t)51*512*2);
  ushort* BtOOh = (ushort*)alloc((size_t)512*1024*2);   // W_out_obj^T
  ushort* BtOOl = (ushort*)alloc((size_t)512*1024*2);
  ushort* BtCOh = (ushort*)alloc((size_t)151*512*2);    // W_cls_obj^T
  ushort* BtCOl = (ushort*)alloc((size_t)151*512*2);
  ushort* BtWCh = (ushort*)alloc((size_t)3072*512*2);   // [Wso@cat3|Woo@cat3]^T
  ushort* BtWCl = (ushort*)alloc((size_t)3072*512*2);
  float*  Gso   = (float*) alloc((size_t)512*3072*4);
  float*  G1    = (float*) alloc((size_t)512*1536*4);
  float*  SumSO = (float*) alloc((size_t)512*1024*4);
  float*  oprob = (float*) alloc((size_t)512*152*4);
  float*  Cobj  = (float*) alloc((size_t)512*512*4);

  // setup-only aliases (regions consumed before Zb/RH first written in loop)
  ushort* BtRELh = (ushort*)Zb;                         // W_rel^T [512][4096]
  ushort* BtRELl = BtRELh + (size_t)512*4096;
  ushort* BtOBJh = BtRELl + (size_t)512*4096;           // W_obj^T
  ushort* BtOBJl = BtOBJh + (size_t)512*4096;
  ushort* BtPRh  = BtOBJl + (size_t)512*4096;           // W_prob^T [512][160]
  ushort* BtPRl  = BtPRh  + (size_t)512*160;
  float*  Wcat   = RH;                                  // fp32 [512][3072]
  float*  Pfp    = RH + (size_t)512*3072;               // fp32 [1024][1536]

  float* HOXr = HX + (size_t)BRt*1024;                  // obj rows of HX

  // ---- setup ----
  softmax_kernel<<<512,64,0,stream>>>(obj_logits, oprob, NOc, NOc, 152, 152);
  TS(stream, W_rel,  4096,512, BtRELh,BtRELl, 4096, 0,0, 4096);
  TS(stream, W_obj,  4096,512, BtOBJh,BtOBJl, 4096, 0,0, 4096);
  TS(stream, W_prob,  151,512, BtPRh, BtPRl,   160, 0,0,  160);
  TS(stream, Wz, 512,512, Bt3h,Bt3l, 512,    0,0, 512);
  TS(stream, Wr, 512,512, Bt3h,Bt3l, 512,  512,0, 512);
  TS(stream, Wh, 512,512, Bt3h,Bt3l, 512, 1024,0, 512);
  TS(stream, Uz, 512,512, BtU2h,BtU2l, 512,   0,0, 512);
  TS(stream, Ur, 512,512, BtU2h,BtU2l, 512, 512,0, 512);
  TS(stream, Uh, 512,512, BtUHh,BtUHl, 512, 0,0, 512);
  TS(stream, W_out_rel, 1024,512, BtORh,BtORl, 1024, 0,0, 1024);
  TS(stream, W_cls_rel,  512, 51, BtCRh,BtCRl,  512, 0,0,  512);
  TS(stream, W_out_obj, 1024,512, BtOOh,BtOOl, 1024, 0,0, 1024);
  TS(stream, W_cls_obj,  512,151, BtCOh,BtCOl,  512, 0,0,  512);
  // xo -> HOXr cols 512..1023 (second GEMM dups into cols 0..511 = ho init)
  Gstd64(stream, obj_fmaps, BtOBJh,BtOBJl, HOXr+512, 512,512,4096, 4096,4096,1024, b_obj,0,0,0);
  Gstd64(stream, oprob,     BtPRh, BtPRl,  HOXr+512, 512,512, 151,  152, 160,1024, b_prob,1,0,-512);
  // xr -> HX cols 512..1023, dup into cols 0..511 (hr init)
  Gstd128(stream, vr, BtRELh,BtRELl, HX+512, BRt,512,4096, 4096,4096,1024, b_rel,0,0,-512);
  // Wcat = [W_so@cat3 | W_oo@cat3]; P = [W_rs@cat3 ; W_ro@cat3]
  Gstd64(stream, W_so, Bt3h,Bt3l, Wcat,            512,1536,512, 512,512,3072, nullptr,0,0,0);
  Gstd64(stream, W_oo, Bt3h,Bt3l, Wcat+1536,       512,1536,512, 512,512,3072, nullptr,0,0,0);
  Gstd64(stream, W_rs, Bt3h,Bt3l, Pfp,             512,1536,512, 512,512,1536, nullptr,0,0,0);
  Gstd64(stream, W_ro, Bt3h,Bt3l, Pfp+512*1536,    512,1536,512, 512,512,1536, nullptr,0,0,0);
  TS(stream, Wcat,  512,3072, BtWCh,BtWCl,  512, 0,0,  512);
  TS(stream, Pfp,  1024,1536, BtPh, BtPl,  1024, 0,0, 1024);

  // ---- T GGNN steps ----
  for (int t = 0; t < Tt; t++) {
    // Gso = ho @ [Wso@cat3 | Woo@cat3]
    Gstd64(stream, HOXr, BtWCh,BtWCl, Gso, 512,3072,512, 1024,512,3072, nullptr,0,0,0);
    // segment sums of old hr
    hipMemsetAsync(SumSO, 0, (size_t)512*1024*4, stream);
    segsum2<<<dim3(8,4,8),64,0,stream>>>(HX, rel_inds, SumSO);
    // G1 = [SumS|SumO] @ ([W_rs;W_ro]@cat3)
    Gstd64(stream, SumSO, BtPh,BtPl, G1, 512,1536,1024, 1024,1024,1536, nullptr,0,0,0);
    // GATE: acc = h @ [Uz|Ur]; fused epilogue -> Zb, RH (rel rows gather Gso, obj rows use G1)
    {
      dim3 g(1024/128, Mall/128);
      gemm_b3<128,128><<<g,256,0,stream>>>(HX, BtU2h,BtU2l, nullptr,
        Mall,1024,512, 1024,512,0, bz,br,0,0,0,
        1, rel_inds, Gso, G1, BRt, Zb, RH, HX);
    }
    // UPD: acc = (r*h) @ Uh; fused epilogue -> GRU update of HX in place
    {
      dim3 g(512/128, Mall/128);
      gemm_b3<128,128><<<g,256,0,stream>>>(RH, BtUHh,BtUHl, nullptr,
        Mall,512,512, 512,512,0, bh,nullptr,0,0,0,
        2, rel_inds, Gso, G1, BRt, Zb, nullptr, HX);
    }
  }

  // ---- heads ----
  float* Crel = Zb;   // Zb free after loop
  Gstd128(stream, HX, BtORh,BtORl, Crel, BRt,512,1024, 1024,1024,512, b_out_rel,0,2,0);
  Gstd128x64(stream, Crel, BtCRh,BtCRl, out_rel_log, BRt,NRc,512, 512,512,NRc, b_cls_rel,0,0,0);
  softmax_kernel<<<BRt,64,0,stream>>>(out_rel_log, out_scpred, NRc, NRc, NRc, NRc);
  Gstd64(stream, HOXr, BtOOh,BtOOl, Cobj, 512,512,1024, 1024,1024,512, b_out_obj,0,2,0);
  Gstd64(stream, Cobj, BtCOh,BtCOl, out_obj_ref, 512,NOc,512, 512,512,NOc, b_cls_obj,0,0,0);
  softmax_kernel<<<512,64,0,stream>>>(out_obj_ref, out_scent, NOc, NOc, NOc, NOc);
  argmax_kernel<<<512,64,0,stream>>>(out_obj_ref, out_preds);
}

// Round 4
// 2169.310 us; speedup vs baseline: 2.1320x; 1.0547x over previous
//
#include <hip/hip_runtime.h>
#include <math.h>

// Problem constants
#define Bn   8
#define Nn   64
#define Rn   2048
#define Dn   4096
#define Hn   512
#define NOc  151
#define NRc  51
#define Tt   3
#define BNt  (Bn*Nn)   // 512 objects
#define BRt  (Bn*Rn)   // 16384 relations
#define Mall (BRt+BNt) // 16896 = rel rows + appended obj rows

typedef __attribute__((ext_vector_type(8))) short short8;
typedef __attribute__((ext_vector_type(4))) float f32x4;

__device__ __forceinline__ float sigmf(float x){ return 1.0f/(1.0f+expf(-x)); }

__device__ __forceinline__ ushort f2bf_rne(float x){
  unsigned u = __float_as_uint(x);
  unsigned r = u + 0x7FFFu + ((u>>16)&1u);
  return (ushort)(r>>16);
}
__device__ __forceinline__ float bf2f(ushort h){
  return __uint_as_float(((unsigned)h)<<16);
}

// ---------------------------------------------------------------------------
// bf16x3 MFMA GEMM. B pre-split bf16 hi/lo planes [N][ldb], k-padded.
// A either fp32 (ASPLIT=0, split in-kernel) or pre-split planes (ASPLIT=1).
// C = Ah*Bh + Ah*Bl + Al*Bh, fp32 accumulate (~fp32 accuracy).
// swz: XCD-aware block swizzle (requires gridDim.y % 8 == 0).
// mode 0: out = act(acc (+Cin) (+bias)) -> fp32 C (dupoff) and/or planes Cph/Cpl (dupp).
// mode 1 (GATE): z=sig(acc_z+g+bz)->Zb ; r*h=sig(acc_r+g+br)*Hf -> RH planes. N=1024.
// mode 2 (UPD):  hn=(1-z)h+z*tanh(acc+g+bh) -> Hf fp32 + HX h-planes. N=512.
// ---------------------------------------------------------------------------
template<int BM,int BN,int ASPLIT>
__global__ __launch_bounds__(256)
void gemm_b3(const float* __restrict__ Af,
             const ushort* __restrict__ Aph, const ushort* __restrict__ Apl,
             const ushort* __restrict__ Bhg, const ushort* __restrict__ Blg,
             float* __restrict__ Cf, const float* __restrict__ Cin,
             int M,int N,int K,int lda,int ldb,int ldc,
             const float* __restrict__ bias, const float* __restrict__ bias2,
             int act,int dupoff,
             ushort* __restrict__ Cph, ushort* __restrict__ Cpl,int ldcp,int dupp,
             int swz,int mode,const int* __restrict__ rel,
             const float* __restrict__ Gso,const float* __restrict__ G1,
             int brt,float* __restrict__ Zb,
             ushort* __restrict__ RHh,ushort* __restrict__ RHl,
             float* __restrict__ Hf,
             ushort* __restrict__ HXph,ushort* __restrict__ HXpl)
{
  constexpr int MT = BM/32, NT = BN/32;
  __shared__ ushort Ah[BM*40], Al[BM*40], Bh[BN*40], Bl[BN*40];

  int bxi = blockIdx.x, byi = blockIdx.y;
  if (swz){
    int id  = byi*gridDim.x + bxi;
    int mch = gridDim.y >> 3;
    int xcd = id & 7, j = id >> 3;
    byi = xcd*mch + j % mch;
    bxi = j / mch;
  }
  const int tid  = threadIdx.x;
  const int lane = tid & 63;
  const int wid  = tid >> 6;
  const int quad = lane >> 4, l15 = lane & 15;
  const int wm = (wid>>1)*(BM/2), wn = (wid&1)*(BN/2);
  const int bm = byi*BM, bn = bxi*BN;

  constexpr int TPR = 256/BM, CPT = 32/TPR;   // A: elements (floats or shorts) per thread
  const int ar = tid / TPR;
  const int ak = (tid % TPR) * CPT;
  constexpr int TPRB = 256/BN, SPT = 32/TPRB;
  const int br_ = tid / TPRB;
  const int bk  = (tid % TPRB) * SPT;
  const int grA = bm + ar;
  const int grB = bn + br_;

  f32x4 acc[MT][NT];
#pragma unroll
  for (int i=0;i<MT;i++)
#pragma unroll
    for (int j=0;j<NT;j++) acc[i][j] = (f32x4){0.f,0.f,0.f,0.f};

  float  avf[ASPLIT ? 1 : CPT];
  short8 avh[ASPLIT ? CPT/8 : 1], avl[ASPLIT ? CPT/8 : 1];
  short8 bvh[SPT/8], bvl[SPT/8];

  auto load_tile = [&](int k0){
    if constexpr (ASPLIT){
      if (grA < M){
#pragma unroll
        for (int i=0;i<CPT/8;i++){
          avh[i] = *(const short8*)(Aph + (size_t)grA*lda + k0 + ak + i*8);
          avl[i] = *(const short8*)(Apl + (size_t)grA*lda + k0 + ak + i*8);
        }
      } else {
#pragma unroll
        for (int i=0;i<CPT/8;i++){
#pragma unroll
          for (int q=0;q<8;q++){ avh[i][q]=0; avl[i][q]=0; }
        }
      }
    } else {
      if (grA < M && ((lda&3)==0) && k0 + ak + CPT <= K) {
        const float* p = Af + (size_t)grA*lda + k0 + ak;
#pragma unroll
        for (int i=0;i<CPT/4;i++) ((float4*)avf)[i] = ((const float4*)p)[i];
      } else {
#pragma unroll
        for (int i=0;i<CPT;i++){
          int gk = k0+ak+i;
          avf[i] = (grA<M && gk<K) ? Af[(size_t)grA*lda+gk] : 0.f;
        }
      }
    }
    if (grB < N){
#pragma unroll
      for (int i=0;i<SPT/8;i++){
        bvh[i] = *(const short8*)(Bhg + (size_t)grB*ldb + k0 + bk + i*8);
        bvl[i] = *(const short8*)(Blg + (size_t)grB*ldb + k0 + bk + i*8);
      }
    } else {
#pragma unroll
      for (int i=0;i<SPT/8;i++){
#pragma unroll
        for (int q=0;q<8;q++){ bvh[i][q]=0; bvl[i][q]=0; }
      }
    }
  };

  load_tile(0);

  for (int k0=0; k0<K; k0+=32) {
    // ---- stage registers -> LDS ----
    if constexpr (ASPLIT){
#pragma unroll
      for (int i=0;i<CPT/8;i++){
        *(short8*)&Ah[ar*40+ak+i*8] = avh[i];
        *(short8*)&Al[ar*40+ak+i*8] = avl[i];
      }
    } else {
      ushort hs[CPT], ls[CPT];
#pragma unroll
      for (int i=0;i<CPT;i++){
        ushort h = f2bf_rne(avf[i]);
        hs[i]=h; ls[i]=f2bf_rne(avf[i]-bf2f(h));
      }
#pragma unroll
      for (int i=0;i<CPT;i+=8){
        short8 vh, vl;
#pragma unroll
        for (int q=0;q<8;q++){ vh[q]=(short)hs[i+q]; vl[q]=(short)ls[i+q]; }
        *(short8*)&Ah[ar*40+ak+i] = vh;
        *(short8*)&Al[ar*40+ak+i] = vl;
      }
    }
#pragma unroll
    for (int i=0;i<SPT/8;i++){
      *(short8*)&Bh[br_*40+bk+i*8] = bvh[i];
      *(short8*)&Bl[br_*40+bk+i*8] = bvl[i];
    }
    __syncthreads();
    if (k0+32 < K) load_tile(k0+32);   // prefetch overlaps MFMA
    {
      short8 afh[MT], afl[MT], bfh[NT], bfl[NT];
#pragma unroll
      for (int i=0;i<MT;i++){
        int o = (wm + i*16 + l15)*40 + quad*8;
        afh[i] = *(const short8*)&Ah[o];
        afl[i] = *(const short8*)&Al[o];
      }
#pragma unroll
      for (int j=0;j<NT;j++){
        int o = (wn + j*16 + l15)*40 + quad*8;
        bfh[j] = *(const short8*)&Bh[o];
        bfl[j] = *(const short8*)&Bl[o];
      }
#pragma unroll
      for (int i=0;i<MT;i++)
#pragma unroll
        for (int j=0;j<NT;j++)
          acc[i][j] = __builtin_amdgcn_mfma_f32_16x16x32_bf16(afh[i], bfh[j], acc[i][j], 0,0,0);
#pragma unroll
      for (int i=0;i<MT;i++)
#pragma unroll
        for (int j=0;j<NT;j++)
          acc[i][j] = __builtin_amdgcn_mfma_f32_16x16x32_bf16(afh[i], bfl[j], acc[i][j], 0,0,0);
#pragma unroll
      for (int i=0;i<MT;i++)
#pragma unroll
        for (int j=0;j<NT;j++)
          acc[i][j] = __builtin_amdgcn_mfma_f32_16x16x32_bf16(afl[i], bfh[j], acc[i][j], 0,0,0);
    }
    __syncthreads();
  }

  // ---- epilogue: C/D layout col=lane&15, row=quad*4+reg ----
  if (mode == 0) {
#pragma unroll
    for (int i=0;i<MT;i++){
      int gm0 = bm + wm + i*16 + quad*4;
#pragma unroll
      for (int j=0;j<NT;j++){
        int gn = bn + wn + j*16 + l15;
        if (gn >= N) continue;
#pragma unroll
        for (int r=0;r<4;r++){
          int gm = gm0 + r;
          if (gm >= M) continue;
          float v = acc[i][j][r];
          if (Cin)  v += Cin[(size_t)gm*ldc+gn];
          if (bias) v += bias[gn];
          if (act==1) v = sigmf(v);
          else if (act==2) v = tanhf(v);
          if (Cf){
            Cf[(size_t)gm*ldc+gn] = v;
            if (dupoff) Cf[(size_t)gm*ldc+gn+dupoff] = v;
          }
          if (Cph){
            ushort h_ = f2bf_rne(v);
            ushort l_ = f2bf_rne(v - bf2f(h_));
            size_t p = (size_t)gm*ldcp + gn;
            Cph[p]=h_; Cpl[p]=l_;
            if (dupp){ Cph[p+dupp]=h_; Cpl[p+dupp]=l_; }
          }
        }
      }
    }
  } else if (mode == 1) {   // GATE
#pragma unroll
    for (int i=0;i<MT;i++){
#pragma unroll
      for (int r=0;r<4;r++){
        int gm = bm + wm + i*16 + quad*4 + r;
        if (gm >= M) continue;
        bool isrel = gm < brt;
        int s=0,o=0; const float* g1row = nullptr;
        if (isrel){ s = rel[gm*3+1]; o = rel[gm*3+2]; }
        else g1row = G1 + (size_t)(gm-brt)*1536;
#pragma unroll
        for (int j=0;j<NT;j++){
          int gn = bn + wn + j*16 + l15;
          float v = acc[i][j][r];
          if (gn < 512){
            float g = isrel ? Gso[(size_t)s*3072+gn] + Gso[(size_t)o*3072+1536+gn]
                            : g1row[gn];
            Zb[(size_t)gm*512+gn] = sigmf(v + g + bias[gn]);
          } else {
            int h = gn - 512;
            float g = isrel ? Gso[(size_t)s*3072+512+h] + Gso[(size_t)o*3072+2048+h]
                            : g1row[512+h];
            float rhv = sigmf(v + g + bias2[h]) * Hf[(size_t)gm*512+h];
            ushort h_ = f2bf_rne(rhv);
            ushort l_ = f2bf_rne(rhv - bf2f(h_));
            RHh[(size_t)gm*512+h]=h_; RHl[(size_t)gm*512+h]=l_;
          }
        }
      }
    }
  } else {                  // UPD
#pragma unroll
    for (int i=0;i<MT;i++){
#pragma unroll
      for (int r=0;r<4;r++){
        int gm = bm + wm + i*16 + quad*4 + r;
        if (gm >= M) continue;
        bool isrel = gm < brt;
        int s=0,o=0; const float* g1row = nullptr;
        if (isrel){ s = rel[gm*3+1]; o = rel[gm*3+2]; }
        else g1row = G1 + (size_t)(gm-brt)*1536;
#pragma unroll
        for (int j=0;j<NT;j++){
          int h = bn + wn + j*16 + l15;
          float v = acc[i][j][r];
          float g = isrel ? Gso[(size_t)s*3072+1024+h] + Gso[(size_t)o*3072+2560+h]
                          : g1row[1024+h];
          float hh = tanhf(v + g + bias[h]);
          size_t ix = (size_t)gm*512+h;
          float z = Zb[ix];
          float hn = (1.f-z)*Hf[ix] + z*hh;
          Hf[ix] = hn;
          ushort h_ = f2bf_rne(hn);
          ushort l_ = f2bf_rne(hn - bf2f(h_));
          size_t p = (size_t)gm*1024+h;
          HXph[p]=h_; HXpl[p]=l_;
        }
      }
    }
  }
}

// ---------------------------------------------------------------------------
// Transpose+split weight: src fp32 [K][N] -> dh/dl bf16 [rowoff+n][koff+k] (ld dld)
// k in [K, gridDim.x*32) zero-padded.
// ---------------------------------------------------------------------------
__global__ __launch_bounds__(256)
void tsplit(const float* __restrict__ src,int K,int N,
            ushort* __restrict__ dh, ushort* __restrict__ dl,
            int dld,int rowoff,int koff)
{
  __shared__ float t[32][33];
  const int tx = threadIdx.x, ty = threadIdx.y;
  const int kb = blockIdx.x*32, nb = blockIdx.y*32;
#pragma unroll
  for (int r=0;r<4;r++){
    int k = kb + ty + r*8, n = nb + tx;
    t[ty+r*8][tx] = (k<K && n<N) ? src[(size_t)k*N + n] : 0.f;
  }
  __syncthreads();
#pragma unroll
  for (int r=0;r<4;r++){
    int n = nb + ty + r*8, k = kb + tx;
    if (n < N){
      float v = t[tx][ty+r*8];
      ushort h = f2bf_rne(v);
      ushort l = f2bf_rne(v - bf2f(h));
      size_t o = (size_t)(rowoff+n)*dld + koff + k;
      dh[o]=h; dl[o]=l;
    }
  }
}

// ---------------------------------------------------------------------------
__global__ __launch_bounds__(64)
void softmax_kernel(const float* __restrict__ in, float* __restrict__ out,
                    int cols, int ldi, int ldo, int padto)
{
  int row = blockIdx.x, lane = threadIdx.x;
  const float* rp = in + (size_t)row*ldi;
  float m = -INFINITY;
  for (int c = lane; c < cols; c += 64) m = fmaxf(m, rp[c]);
  for (int off = 32; off; off >>= 1) m = fmaxf(m, __shfl_xor(m, off));
  float s = 0.f;
  for (int c = lane; c < cols; c += 64) s += expf(rp[c]-m);
  for (int off = 32; off; off >>= 1) s += __shfl_xor(s, off);
  float inv = 1.f/s;
  float* op = out + (size_t)row*ldo;
  for (int c = lane; c < padto; c += 64)
    op[c] = (c < cols) ? expf(rp[c]-m)*inv : 0.f;
}

__global__ __launch_bounds__(64)
void argmax_kernel(const float* __restrict__ ref, float* __restrict__ preds)
{
  int row = blockIdx.x, lane = threadIdx.x;
  const float* rp = ref + (size_t)row*NOc;
  float bv = -INFINITY; int bi = NOc;
  for (int c = 1+lane; c < NOc; c += 64) { float v = rp[c]; if (v > bv) { bv=v; bi=c; } }
  for (int off=32; off; off>>=1) {
    float ov = __shfl_xor(bv, off); int oi = __shfl_xor(bi, off);
    if (ov > bv || (ov == bv && oi < bi)) { bv = ov; bi = oi; }
  }
  if (lane==0) preds[row] = (float)bi;
}

// segment sums of Hf rel rows (ld 512) into SumSO [512][1024]
__global__ __launch_bounds__(64)
void segsum2(const float* __restrict__ Hf, const int* __restrict__ rel_inds,
             float* __restrict__ SumSO)
{
  __shared__ float accS[64][64];
  __shared__ float accO[64][64];
  const int t = threadIdx.x;
  const int hb = blockIdx.x*64;
  const int img = blockIdx.z;
  const int relbase = img*Rn + blockIdx.y*(Rn/4);
  for (int ob=0; ob<64; ob++){ accS[ob][t]=0.f; accO[ob][t]=0.f; }
  for (int i=0;i<Rn/4;i++){
    int r = relbase+i;
    int s = rel_inds[r*3+1] - img*64;
    int o = rel_inds[r*3+2] - img*64;
    float v = Hf[(size_t)r*512 + hb + t];
    accS[s][t]+=v; accO[o][t]+=v;
  }
  for (int ob=0;ob<64;ob++){
    size_t rowb = (size_t)(img*64+ob)*1024 + hb + t;
    atomicAdd(&SumSO[rowb],     accS[ob][t]);
    atomicAdd(&SumSO[rowb+512], accO[ob][t]);
  }
}

// ---------------------------------------------------------------------------
#define FZ0 0,nullptr,nullptr,nullptr,0,nullptr,nullptr,nullptr,nullptr,nullptr,nullptr

static void TS(hipStream_t s,const float*src,int K,int N,ushort*dh,ushort*dl,
               int dld,int rowoff,int koff,int Kpad){
  dim3 g(Kpad/32,(N+31)/32);
  tsplit<<<g,dim3(32,8),0,s>>>(src,K,N,dh,dl,dld,rowoff,koff);
}

extern "C" void kernel_launch(void* const* d_in, const int* in_sizes, int n_in,
                              void* d_out, int out_size, void* d_ws, size_t ws_size,
                              hipStream_t stream) {
  (void)in_sizes; (void)n_in; (void)out_size; (void)ws_size;
  const int*   rel_inds   = (const int*)  d_in[1];
  const float* obj_fmaps  = (const float*)d_in[2];
  const float* obj_logits = (const float*)d_in[3];
  const float* vr         = (const float*)d_in[4];
  const float* W_obj      = (const float*)d_in[5];
  const float* b_obj      = (const float*)d_in[6];
  const float* W_rel      = (const float*)d_in[7];
  const float* b_rel      = (const float*)d_in[8];
  const float* W_prob     = (const float*)d_in[9];
  const float* b_prob     = (const float*)d_in[10];
  const float* W_so       = (const float*)d_in[11];
  const float* W_oo       = (const float*)d_in[12];
  const float* W_rs       = (const float*)d_in[13];
  const float* W_ro       = (const float*)d_in[14];
  const float* Wz         = (const float*)d_in[15];
  const float* Uz         = (const float*)d_in[16];
  const float* bz         = (const float*)d_in[17];
  const float* Wr         = (const float*)d_in[18];
  const float* Ur         = (const float*)d_in[19];
  const float* br         = (const float*)d_in[20];
  const float* Wh         = (const float*)d_in[21];
  const float* Uh         = (const float*)d_in[22];
  const float* bh         = (const float*)d_in[23];
  const float* W_out_rel  = (const float*)d_in[24];
  const float* b_out_rel  = (const float*)d_in[25];
  const float* W_cls_rel  = (const float*)d_in[26];
  const float* b_cls_rel  = (const float*)d_in[27];
  const float* W_out_obj  = (const float*)d_in[28];
  const float* b_out_obj  = (const float*)d_in[29];
  const float* W_cls_obj  = (const float*)d_in[30];
  const float* b_cls_obj  = (const float*)d_in[31];

  // output layout (floats): obj_ref | obj_preds | rel_logits | scpred | scent
  float* out          = (float*)d_out;
  float* out_obj_ref  = out;
  float* out_preds    = out + 77312;
  float* out_rel_log  = out + 77824;
  float* out_scpred   = out + 913408;
  float* out_scent    = out + 1748992;

  // ---- workspace carve ----
  char* base = (char*)d_ws; size_t off = 0;
  auto alloc = [&](size_t bytes)->void*{ void* p = base+off; off = (off+bytes+255)&~(size_t)255; return p; };
  float*  Hf    = (float*) alloc((size_t)Mall*512*4);    // fp32 hidden state (hr / ho)
  ushort* HXph  = (ushort*)alloc((size_t)Mall*1024*2);   // planes: [h | x]
  ushort* HXpl  = (ushort*)alloc((size_t)Mall*1024*2);
  ushort* RHh   = (ushort*)alloc((size_t)Mall*512*2);    // r*h planes; reused as Crel planes
  ushort* RHl   = (ushort*)alloc((size_t)Mall*512*2);
  float*  Zb    = (float*) alloc((size_t)Mall*512*4);    // z gate; setup scratch alias
  ushort* Bt3h  = (ushort*)alloc((size_t)1536*512*2);    // [Wz|Wr|Wh]^T
  ushort* Bt3l  = (ushort*)alloc((size_t)1536*512*2);
  ushort* BtU2h = (ushort*)alloc((size_t)1024*512*2);    // [Uz|Ur]^T
  ushort* BtU2l = (ushort*)alloc((size_t)1024*512*2);
  ushort* BtUHh = (ushort*)alloc((size_t)512*512*2);     // Uh^T
  ushort* BtUHl = (ushort*)alloc((size_t)512*512*2);
  ushort* BtPh  = (ushort*)alloc((size_t)1536*1024*2);   // ([W_rs;W_ro]@cat3)^T
  ushort* BtPl  = (ushort*)alloc((size_t)1536*1024*2);
  ushort* BtORh = (ushort*)alloc((size_t)512*1024*2);    // W_out_rel^T
  ushort* BtORl = (ushort*)alloc((size_t)512*1024*2);
  ushort* BtCRh = (ushort*)alloc((size_t)64*512*2);      // W_cls_rel^T
  ushort* BtCRl = (ushort*)alloc((size_t)64*512*2);
  ushort* BtOOh = (ushort*)alloc((size_t)512*1024*2);    // W_out_obj^T
  ushort* BtOOl = (ushort*)alloc((size_t)512*1024*2);
  ushort* BtCOh = (ushort*)alloc((size_t)152*512*2);     // W_cls_obj^T
  ushort* BtCOl = (ushort*)alloc((size_t)152*512*2);
  ushort* BtWCh = (ushort*)alloc((size_t)3072*512*2);    // [Wso@cat3|Woo@cat3]^T
  ushort* BtWCl = (ushort*)alloc((size_t)3072*512*2);
  float*  Gso   = (float*) alloc((size_t)512*3072*4);
  float*  G1    = (float*) alloc((size_t)512*1536*4);
  float*  SumSO = (float*) alloc((size_t)512*1024*4);
  float*  oprob = (float*) alloc((size_t)512*152*4);
  float*  Xotmp = (float*) alloc((size_t)512*512*4);
  ushort* COph  = (ushort*)alloc((size_t)512*512*2);     // Cobj planes
  ushort* COpl  = (ushort*)alloc((size_t)512*512*2);

  // setup-only aliases inside Zb (34.6 MB; aliases total ~29.7 MB)
  ushort* BtRELh = (ushort*)Zb;                          // W_rel^T [512][4096]
  ushort* BtRELl = BtRELh + (size_t)512*4096;
  ushort* BtOBJh = BtRELl + (size_t)512*4096;            // W_obj^T
  ushort* BtOBJl = BtOBJh + (size_t)512*4096;
  ushort* BtPRh  = BtOBJl + (size_t)512*4096;            // W_prob^T [512][160]
  ushort* BtPRl  = BtPRh  + (size_t)512*160;
  float*  Wcat   = (float*)(BtPRl + (size_t)512*160);    // fp32 [512][3072]
  float*  Pfp    = Wcat + (size_t)512*3072;              // fp32 [1024][1536]

  // ---- setup ----
  softmax_kernel<<<512,64,0,stream>>>(obj_logits, oprob, NOc, NOc, 152, 152);
  TS(stream, W_rel,  4096,512, BtRELh,BtRELl, 4096, 0,0, 4096);
  TS(stream, W_obj,  4096,512, BtOBJh,BtOBJl, 4096, 0,0, 4096);
  TS(stream, W_prob,  151,512, BtPRh, BtPRl,   160, 0,0,  160);
  TS(stream, Wz, 512,512, Bt3h,Bt3l, 512,    0,0, 512);
  TS(stream, Wr, 512,512, Bt3h,Bt3l, 512,  512,0, 512);
  TS(stream, Wh, 512,512, Bt3h,Bt3l, 512, 1024,0, 512);
  TS(stream, Uz, 512,512, BtU2h,BtU2l, 512,   0,0, 512);
  TS(stream, Ur, 512,512, BtU2h,BtU2l, 512, 512,0, 512);
  TS(stream, Uh, 512,512, BtUHh,BtUHl, 512, 0,0, 512);
  TS(stream, W_out_rel, 1024,512, BtORh,BtORl, 1024, 0,0, 1024);
  TS(stream, W_cls_rel,  512, 51, BtCRh,BtCRl,  512, 0,0,  512);
  TS(stream, W_out_obj, 1024,512, BtOOh,BtOOl, 1024, 0,0, 1024);
  TS(stream, W_cls_obj,  512,151, BtCOh,BtCOl,  512, 0,0,  512);

  // xo: Xotmp = obj_fmaps@W_obj + b_obj ; then += oprob@W_prob + b_prob
  //     -> Hf obj rows (ho init) + planes x-cols & dup h-cols
  {
    dim3 g(8,8);
    gemm_b3<64,64,0><<<g,256,0,stream>>>(obj_fmaps,nullptr,nullptr,BtOBJh,BtOBJl,
      Xotmp,nullptr, 512,512,4096, 4096,4096,512, b_obj,nullptr,0,0,
      nullptr,nullptr,0,0, 1, FZ0);
    gemm_b3<64,64,0><<<g,256,0,stream>>>(oprob,nullptr,nullptr,BtPRh,BtPRl,
      Hf+(size_t)BRt*512, Xotmp, 512,512,151, 152,160,512, b_prob,nullptr,0,0,
      HXph+(size_t)BRt*1024+512, HXpl+(size_t)BRt*1024+512, 1024, -512, 1, FZ0);
  }
  // xr: Hf rel rows (hr init) + planes x-cols & dup h-cols
  {
    dim3 g(2,256);
    gemm_b3<64,256,0><<<g,256,0,stream>>>(vr,nullptr,nullptr,BtRELh,BtRELl,
      Hf,nullptr, BRt,512,4096, 4096,4096,512, b_rel,nullptr,0,0,
      HXph+512, HXpl+512, 1024, -512, 1, FZ0);
  }
  // Wcat = [W_so@cat3 | W_oo@cat3]; P = [W_rs@cat3 ; W_ro@cat3]
  {
    dim3 g(24,8);
    gemm_b3<64,64,0><<<g,256,0,stream>>>(W_so,nullptr,nullptr,Bt3h,Bt3l,
      Wcat,nullptr, 512,1536,512, 512,512,3072, nullptr,nullptr,0,0, nullptr,nullptr,0,0, 1, FZ0);
    gemm_b3<64,64,0><<<g,256,0,stream>>>(W_oo,nullptr,nullptr,Bt3h,Bt3l,
      Wcat+1536,nullptr, 512,1536,512, 512,512,3072, nullptr,nullptr,0,0, nullptr,nullptr,0,0, 1, FZ0);
    gemm_b3<64,64,0><<<g,256,0,stream>>>(W_rs,nullptr,nullptr,Bt3h,Bt3l,
      Pfp,nullptr, 512,1536,512, 512,512,1536, nullptr,nullptr,0,0, nullptr,nullptr,0,0, 1, FZ0);
    gemm_b3<64,64,0><<<g,256,0,stream>>>(W_ro,nullptr,nullptr,Bt3h,Bt3l,
      Pfp+(size_t)512*1536,nullptr, 512,1536,512, 512,512,1536, nullptr,nullptr,0,0, nullptr,nullptr,0,0, 1, FZ0);
  }
  TS(stream, Wcat,  512,3072, BtWCh,BtWCl,  512, 0,0,  512);
  TS(stream, Pfp,  1024,1536, BtPh, BtPl,  1024, 0,0, 1024);

  // ---- T GGNN steps ----
  for (int t = 0; t < Tt; t++) {
    // Gso = ho @ [Wso@cat3 | Woo@cat3]   (A = obj h-planes)
    {
      dim3 g(48,8);
      gemm_b3<64,64,1><<<g,256,0,stream>>>(nullptr,HXph+(size_t)BRt*1024,HXpl+(size_t)BRt*1024,
        BtWCh,BtWCl, Gso,nullptr, 512,3072,512, 1024,512,3072,
        nullptr,nullptr,0,0, nullptr,nullptr,0,0, 1, FZ0);
    }
    hipMemsetAsync(SumSO, 0, (size_t)512*1024*4, stream);
    segsum2<<<dim3(8,4,8),64,0,stream>>>(Hf, rel_inds, SumSO);
    // G1 = [SumS|SumO] @ ([W_rs;W_ro]@cat3)
    {
      dim3 g(24,8);
      gemm_b3<64,64,0><<<g,256,0,stream>>>(SumSO,nullptr,nullptr,BtPh,BtPl,
        G1,nullptr, 512,1536,1024, 1024,1024,1536,
        nullptr,nullptr,0,0, nullptr,nullptr,0,0, 1, FZ0);
    }
    // GATE: acc = h @ [Uz|Ur] -> Zb, RH planes
    {
      dim3 g(8,136);
      gemm_b3<128,128,1><<<g,256,0,stream>>>(nullptr,HXph,HXpl,BtU2h,BtU2l,
        nullptr,nullptr, Mall,1024,512, 1024,512,0, bz,br,0,0,
        nullptr,nullptr,0,0, 1,
        1, rel_inds, Gso, G1, BRt, Zb, RHh,RHl, Hf, nullptr,nullptr);
    }
    // UPD: acc = (r*h) @ Uh -> Hf + h-planes
    {
      dim3 g(4,136);
      gemm_b3<128,128,1><<<g,256,0,stream>>>(nullptr,RHh,RHl,BtUHh,BtUHl,
        nullptr,nullptr, Mall,512,512, 512,512,0, bh,nullptr,0,0,
        nullptr,nullptr,0,0, 1,
        2, rel_inds, Gso, G1, BRt, Zb, nullptr,nullptr, Hf, HXph,HXpl);
    }
  }

  // ---- heads ----
  // Crel = tanh([hr|xr]@W_out_rel + b) -> planes (reuse RH)
  {
    dim3 g(4,128);
    gemm_b3<128,128,1><<<g,256,0,stream>>>(nullptr,HXph,HXpl,BtORh,BtORl,
      nullptr,nullptr, BRt,512,1024, 1024,1024,0, b_out_rel,nullptr,2,0,
      RHh,RHl,512,0, 1, FZ0);
  }
  {
    dim3 g(1,256);
    gemm_b3<64,64,1><<<g,256,0,stream>>>(nullptr,RHh,RHl,BtCRh,BtCRl,
      out_rel_log,nullptr, BRt,NRc,512, 512,512,NRc, b_cls_rel,nullptr,0,0,
      nullptr,nullptr,0,0, 1, FZ0);
  }
  softmax_kernel<<<BRt,64,0,stream>>>(out_rel_log, out_scpred, NRc, NRc, NRc, NRc);
  // Cobj = tanh([ho|xo]@W_out_obj + b) -> planes
  {
    dim3 g(8,8);
    gemm_b3<64,64,1><<<g,256,0,stream>>>(nullptr,HXph+(size_t)BRt*1024,HXpl+(size_t)BRt*1024,
      BtOOh,BtOOl, nullptr,nullptr, 512,512,1024, 1024,1024,0, b_out_obj,nullptr,2,0,
      COph,COpl,512,0, 1, FZ0);
  }
  {
    dim3 g(3,8);
    gemm_b3<64,64,1><<<g,256,0,stream>>>(nullptr,COph,COpl,BtCOh,BtCOl,
      out_obj_ref,nullptr, 512,NOc,512, 512,512,NOc, b_cls_obj,nullptr,0,0,
      nullptr,nullptr,0,0, 1, FZ0);
  }
  softmax_kernel<<<512,64,0,stream>>>(out_obj_ref, out_scent, NOc, NOc, NOc, NOc);
  argmax_kernel<<<512,64,0,stream>>>(out_obj_ref, out_preds);
}